// Round 5
// baseline (647.443 us; speedup 1.0000x reference)
//
#include <hip/hip_runtime.h>
#include <cstdint>
#include <cstddef>

#define DEV __device__ __forceinline__

typedef __attribute__((ext_vector_type(8))) short short8;
typedef __attribute__((ext_vector_type(4))) float f32x4;
typedef __attribute__((ext_vector_type(4))) unsigned short ushort4v;

DEV unsigned short f2bf(float f){
  union { float f; unsigned int i; } v; v.f = f;
  unsigned int r = v.i + 0x7fffu + ((v.i >> 16) & 1u);
  return (unsigned short)(r >> 16);
}

DEV void gld_lds16(const unsigned short* g, unsigned short* lds){
  __builtin_amdgcn_global_load_lds((const __attribute__((address_space(1))) void*)g,
                                   (__attribute__((address_space(3))) void*)lds, 16, 0, 0);
}

// =================== 128x128 8-wave pipelined GEMM, 2 blocks/CU ===================
// C[M,N] = A[M,K](bf16) @ Bt[N,K]^T(bf16) + bias.  BK=64, 2 phases/K-tile.
// LDS 64 KiB: 2 bufs x (A 16KB + B 16KB); rows of 64 halves (128B, 8 slots x 16B),
// slot swizzle phys = logical ^ (row&7), staged via pre-swizzled global source col.
// A row placement: LDS row rho = mh*64 + h*32 + j for global row r = h*64 + mh*32 + j
// (issue mh covers exactly the rows phase mh reads: union over waves wr=h).
// Schedule per tile u (buf p=u&1): PH0 {read B(all)+A-chunk0; stage B01(u+1)->p^1;
// barrier; 8 MFMA; vmcnt(2); barrier}  PH1 {read A-chunk1; stage A01(u+1)->p^1;
// barrier; 8 MFMA; vmcnt(1); barrier}.  Waits counted (0 only at final tile);
// stage targets last-read >=2 barriers earlier (race-free by construction).
template<int EPI>
__global__ __launch_bounds__(512, 4)
void gemm128p(const unsigned short* __restrict__ A,
              const unsigned short* __restrict__ Bt,
              const float* __restrict__ bias,
              void* __restrict__ C, int M, int N, int K)
{
  __shared__ __align__(16) unsigned short lds[32768];   // 64 KiB

  const int tid = threadIdx.x, wid = tid >> 6, l = tid & 63;
  const int wr = wid >> 2, wc = wid & 3;   // 2 x 4 waves; per-wave out 64x32

  const int nbm = M / 128, nbn = N / 128;
  const int nwg = nbm * nbn;
  const int q8 = nwg >> 3, r8 = nwg & 7;
  const int xcd = blockIdx.x & 7, within = blockIdx.x >> 3;
  const int wg = (xcd < r8 ? xcd * (q8 + 1) : r8 * (q8 + 1) + (xcd - r8) * q8) + within;
  const int mb = (wg % nbm) * 128, nb = (wg / nbm) * 128;

  const int nk = K / 64;

  // staging constants: thread t stages 16B; logical slot s = (t&7)^((t>>3)&7)
  const int sA_row = (tid >> 8) * 64 + ((tid >> 3) & 31);   // + i*32
  const int sB_row = tid >> 3;                              // + i*64
  const int scol = ((tid & 7) ^ ((tid >> 3) & 7)) * 8;

  // read constants: lane l -> row rl within 16-row frag, k-group kg
  const int rl = l & 15, kg = l >> 4;
  const int so0 = ((kg)     ^ (l & 7)) * 8;   // ks=0 slot byte offset (halves)
  const int so1 = ((4 + kg) ^ (l & 7)) * 8;   // ks=1

  f32x4 acc[4][2];
  #pragma unroll
  for (int m = 0; m < 4; m++)
    #pragma unroll
    for (int n = 0; n < 2; n++) acc[m][n] = (f32x4){0.f, 0.f, 0.f, 0.f};

#define STAGE_A(i, tt, pp) \
  gld_lds16(A + (size_t)(mb + sA_row + (i)*32) * K + (size_t)(tt)*64 + scol, \
            lds + (pp)*16384 + (i)*4096 + tid*8)
#define STAGE_B(i, tt, pp) \
  gld_lds16(Bt + (size_t)(nb + (i)*64 + sB_row) * K + (size_t)(tt)*64 + scol, \
            lds + (pp)*16384 + 8192 + (i)*4096 + tid*8)
#define BAR() do { asm volatile("" ::: "memory"); __builtin_amdgcn_s_barrier(); \
                   asm volatile("" ::: "memory"); } while(0)

  // prologue: tile 0 -> buf 0
  STAGE_B(0, 0, 0); STAGE_B(1, 0, 0); STAGE_A(0, 0, 0); STAGE_A(1, 0, 0);
  asm volatile("s_waitcnt vmcnt(1)" ::: "memory");   // B0,B1,A0 landed; A1 may fly
  BAR();

  for (int u = 0; u < nk; u++){
    const int p = u & 1;
    const unsigned short* buf = lds + p * 16384;
    const unsigned short* bB  = buf + 8192 + (wc * 32 + rl) * 64;
    short8 bfr[2][2], af[2][2];

    // ---- PH0: read all B + A-chunk0 (LDS rows 0..63 = phase-0 rows) ----
    #pragma unroll
    for (int n = 0; n < 2; n++){
      bfr[n][0] = *(const short8*)(bB + n * 1024 + so0);
      bfr[n][1] = *(const short8*)(bB + n * 1024 + so1);
    }
    {
      const unsigned short* aB = buf + (wr * 32 + rl) * 64;   // mh=0 region
      #pragma unroll
      for (int f = 0; f < 2; f++){
        af[f][0] = *(const short8*)(aB + f * 1024 + so0);
        af[f][1] = *(const short8*)(aB + f * 1024 + so1);
      }
    }
    if (u + 1 < nk){ STAGE_B(0, u + 1, p ^ 1); STAGE_B(1, u + 1, p ^ 1); }
    BAR();
    __builtin_amdgcn_s_setprio(1);
    #pragma unroll
    for (int f = 0; f < 2; f++)
      #pragma unroll
      for (int n = 0; n < 2; n++){
        acc[f][n] = __builtin_amdgcn_mfma_f32_16x16x32_bf16(af[f][0], bfr[n][0], acc[f][n], 0, 0, 0);
        acc[f][n] = __builtin_amdgcn_mfma_f32_16x16x32_bf16(af[f][1], bfr[n][1], acc[f][n], 0, 0, 0);
      }
    __builtin_amdgcn_s_setprio(0);
    if (u + 1 < nk) asm volatile("s_waitcnt vmcnt(2)" ::: "memory");  // A1(u) retired
    else            asm volatile("s_waitcnt vmcnt(0)" ::: "memory");
    BAR();

    // ---- PH1: read A-chunk1 (LDS rows 64..127 = phase-1 rows) ----
    {
      const unsigned short* aB = buf + 4096 + (wr * 32 + rl) * 64;   // mh=1 region
      #pragma unroll
      for (int f = 0; f < 2; f++){
        af[f][0] = *(const short8*)(aB + f * 1024 + so0);
        af[f][1] = *(const short8*)(aB + f * 1024 + so1);
      }
    }
    if (u + 1 < nk){ STAGE_A(0, u + 1, p ^ 1); STAGE_A(1, u + 1, p ^ 1); }
    BAR();
    __builtin_amdgcn_s_setprio(1);
    #pragma unroll
    for (int f = 0; f < 2; f++)
      #pragma unroll
      for (int n = 0; n < 2; n++){
        acc[2 + f][n] = __builtin_amdgcn_mfma_f32_16x16x32_bf16(af[f][0], bfr[n][0], acc[2 + f][n], 0, 0, 0);
        acc[2 + f][n] = __builtin_amdgcn_mfma_f32_16x16x32_bf16(af[f][1], bfr[n][1], acc[2 + f][n], 0, 0, 0);
      }
    __builtin_amdgcn_s_setprio(0);
    if (u + 1 < nk) asm volatile("s_waitcnt vmcnt(1)" ::: "memory");  // keep A1(u+1) in flight
    BAR();
  }
#undef BAR
#undef STAGE_A
#undef STAGE_B

  // epilogue
  #pragma unroll
  for (int n = 0; n < 2; n++){
    const int col = nb + wc * 32 + n * 16 + rl;
    const float bv = bias ? bias[col] : 0.f;
    #pragma unroll
    for (int m = 0; m < 4; m++){
      const int row0 = mb + wr * 64 + m * 16 + kg * 4;
      #pragma unroll
      for (int jj = 0; jj < 4; jj++){
        float v = acc[m][n][jj] + bv;
        size_t idx = (size_t)(row0 + jj) * N + col;
        if (EPI == 0)       ((float*)C)[idx] = v;
        else if (EPI == 3)  __builtin_nontemporal_store(v, &((float*)C)[idx]);
        else if (EPI == 1)  ((unsigned short*)C)[idx] = f2bf(v);
        else { v = v > 0.f ? v : 0.f; ((unsigned short*)C)[idx] = f2bf(v); }
      }
    }
  }
}

// ---------------- GEMM (m97-style 2-phase): C[M,N] = A@Bt^T + bias ----------------
template<int BM, int BN, int EPI>
__global__ __launch_bounds__(256, 2)
void gemm_bt(const unsigned short* __restrict__ A,
             const unsigned short* __restrict__ Bt,
             const float* __restrict__ bias,
             void* __restrict__ C, int M, int N, int K)
{
  constexpr int MF = BM / 32, NF = BN / 32;
  constexpr int LA = BM / 64, LB = BN / 64;
  __shared__ __align__(16) unsigned short lds[2 * (BM + BN) * 32];

  const int tid = threadIdx.x, w = tid >> 6, l = tid & 63;
  const int wr = w >> 1, wc = w & 1;

  const int nbm = M / BM, nbn = N / BN;
  const int nwg = nbm * nbn;
  const int q8 = nwg >> 3, r8 = nwg & 7;
  const int xcd = blockIdx.x & 7, within = blockIdx.x >> 3;
  const int wg = (xcd < r8 ? xcd * (q8 + 1) : r8 * (q8 + 1) + (xcd - r8) * q8) + within;
  const int mb = (wg % nbm) * BM, nb = (wg / nbm) * BN;

  unsigned short* As0 = lds;
  unsigned short* Bs0 = lds + BM * 32;
  unsigned short* As1 = lds + (BM + BN) * 32;
  unsigned short* Bs1 = As1 + BM * 32;

  f32x4 acc[MF][NF];
  #pragma unroll
  for (int m = 0; m < MF; m++)
    #pragma unroll
    for (int n = 0; n < NF; n++) acc[m][n] = (f32x4){0.f, 0.f, 0.f, 0.f};

  const int srow = l >> 2;
  const int scol = (((l & 3) ^ ((l >> 2) & 3) ^ ((l >> 4) & 3)) * 8);
  const int rswz = (l & 3) ^ ((l >> 2) & 3);

  #define STAGE(Ad, Bd, k0) do { \
    _Pragma("unroll") \
    for (int i = 0; i < LA; i++){ \
      int chunk = i * 4 + w; \
      gld_lds16(A + (size_t)(mb + chunk * 16 + srow) * K + (k0) + scol, (Ad) + chunk * 512); \
    } \
    _Pragma("unroll") \
    for (int i = 0; i < LB; i++){ \
      int chunk = i * 4 + w; \
      gld_lds16(Bt + (size_t)(nb + chunk * 16 + srow) * K + (k0) + scol, (Bd) + chunk * 512); \
    } } while(0)

  STAGE(As0, Bs0, 0);
  const int nk = K / 32;
  const int rdoff = ((l >> 4) ^ rswz) * 8;
  for (int kt = 0; kt < nk; kt++){
    __syncthreads();
    unsigned short* Ac = (kt & 1) ? As1 : As0;
    unsigned short* Bc = (kt & 1) ? Bs1 : Bs0;
    if (kt + 1 < nk){
      unsigned short* An = (kt & 1) ? As0 : As1;
      unsigned short* Bn = (kt & 1) ? Bs0 : Bs1;
      STAGE(An, Bn, (kt + 1) * 32);
    }
    short8 af[MF], bfr[NF];
    #pragma unroll
    for (int m = 0; m < MF; m++)
      af[m] = *(const short8*)(Ac + (wr * (BM / 2) + m * 16 + (l & 15)) * 32 + rdoff);
    #pragma unroll
    for (int n = 0; n < NF; n++)
      bfr[n] = *(const short8*)(Bc + (wc * (BN / 2) + n * 16 + (l & 15)) * 32 + rdoff);
    #pragma unroll
    for (int m = 0; m < MF; m++)
      #pragma unroll
      for (int n = 0; n < NF; n++)
        acc[m][n] = __builtin_amdgcn_mfma_f32_16x16x32_bf16(af[m], bfr[n], acc[m][n], 0, 0, 0);
  }
  #undef STAGE

  #pragma unroll
  for (int n = 0; n < NF; n++){
    const int col = nb + wc * (BN / 2) + n * 16 + (l & 15);
    const float bv = bias ? bias[col] : 0.f;
    #pragma unroll
    for (int m = 0; m < MF; m++){
      const int row0 = mb + wr * (BM / 2) + m * 16 + ((l >> 4) << 2);
      #pragma unroll
      for (int jj = 0; jj < 4; jj++){
        float v = acc[m][n][jj] + bv;
        size_t idx = (size_t)(row0 + jj) * N + col;
        if (EPI == 0)       ((float*)C)[idx] = v;
        else if (EPI == 3)  __builtin_nontemporal_store(v, &((float*)C)[idx]);
        else if (EPI == 1)  ((unsigned short*)C)[idx] = f2bf(v);
        else { v = v > 0.f ? v : 0.f; ((unsigned short*)C)[idx] = f2bf(v); }
      }
    }
  }
}

// ---------------- Flash attention: 64 q-rows / block (4 waves x 16), dh=64, H=16 ----------------
template<int CAUSAL>
__global__ __launch_bounds__(256)
void attn_kernel(const unsigned short* __restrict__ Qb, int ldq,
                 const unsigned short* __restrict__ Kb, int ldk,
                 const unsigned short* __restrict__ Vb, int ldv,
                 unsigned short* __restrict__ Ob, int ldo)
{
  constexpr int S = 1024;
  __shared__ __align__(16) unsigned short vt[64][40];
  __shared__ __align__(16) unsigned short plds[4][16][40];
  const int tid = threadIdx.x, w = tid >> 6, l = tid & 63;
  const int qt = blockIdx.x, bh = blockIdx.y;
  const int b = bh >> 4, h = bh & 15;
  const int hoff = h * 64;
  const size_t rb = (size_t)b * S;

  const int qrow = qt * 64 + w * 16 + (l & 15);
  const unsigned short* qp = Qb + (rb + qrow) * ldq + hoff + ((l >> 4) * 8);
  short8 qf0 = *(const short8*)qp;
  short8 qf1 = *(const short8*)(qp + 32);

  float m_run[4] = {-1e30f, -1e30f, -1e30f, -1e30f};
  float l_run[4] = {0.f, 0.f, 0.f, 0.f};
  f32x4 oacc[4];
  #pragma unroll
  for (int t = 0; t < 4; t++) oacc[t] = (f32x4){0.f, 0.f, 0.f, 0.f};

  const int qmax = qt * 64 + w * 16 + 15;
  const int nkeys = CAUSAL ? (qt * 64 + 64) : S;
  const int skey = tid >> 3, sd8 = (tid & 7) * 8;

  for (int kb = 0; kb < nkeys; kb += 32){
    short8 vv = *(const short8*)(Vb + (rb + kb + skey) * ldv + hoff + sd8);
    #pragma unroll
    for (int i = 0; i < 8; i++) vt[sd8 + i][skey] = (unsigned short)vv[i];
    __syncthreads();
    if (!CAUSAL || kb <= qmax){
      f32x4 sc[2];
      #pragma unroll
      for (int g = 0; g < 2; g++){
        const unsigned short* kp = Kb + (rb + kb + g * 16 + (l & 15)) * ldk + hoff + ((l >> 4) * 8);
        short8 kf0 = *(const short8*)kp;
        short8 kf1 = *(const short8*)(kp + 32);
        f32x4 z = (f32x4){0.f, 0.f, 0.f, 0.f};
        z = __builtin_amdgcn_mfma_f32_16x16x32_bf16(qf0, kf0, z, 0, 0, 0);
        z = __builtin_amdgcn_mfma_f32_16x16x32_bf16(qf1, kf1, z, 0, 0, 0);
        sc[g] = z;
      }
      #pragma unroll
      for (int jj = 0; jj < 4; jj++){
        float s0 = sc[0][jj] * 0.125f, s1 = sc[1][jj] * 0.125f;
        if (CAUSAL){
          int q = qt * 64 + w * 16 + ((l >> 4) << 2) + jj;
          if (kb + (l & 15) > q)      s0 = -1e30f;
          if (kb + 16 + (l & 15) > q) s1 = -1e30f;
        }
        float mx = fmaxf(s0, s1);
        mx = fmaxf(mx, __shfl_xor(mx, 1));
        mx = fmaxf(mx, __shfl_xor(mx, 2));
        mx = fmaxf(mx, __shfl_xor(mx, 4));
        mx = fmaxf(mx, __shfl_xor(mx, 8));
        float mnew = fmaxf(m_run[jj], mx);
        float scal = __expf(m_run[jj] - mnew);
        m_run[jj] = mnew;
        float p0 = __expf(s0 - mnew), p1 = __expf(s1 - mnew);
        float rs = p0 + p1;
        rs += __shfl_xor(rs, 1); rs += __shfl_xor(rs, 2);
        rs += __shfl_xor(rs, 4); rs += __shfl_xor(rs, 8);
        l_run[jj] = l_run[jj] * scal + rs;
        #pragma unroll
        for (int t = 0; t < 4; t++) oacc[t][jj] *= scal;
        int qr = ((l >> 4) << 2) + jj;
        plds[w][qr][l & 15]      = f2bf(p0);
        plds[w][qr][16 + (l & 15)] = f2bf(p1);
      }
      asm volatile("s_waitcnt lgkmcnt(0)" ::: "memory");
      short8 pf = *(const short8*)&plds[w][l & 15][(l >> 4) * 8];
      #pragma unroll
      for (int t = 0; t < 4; t++){
        short8 vf = *(const short8*)&vt[t * 16 + (l & 15)][(l >> 4) * 8];
        oacc[t] = __builtin_amdgcn_mfma_f32_16x16x32_bf16(pf, vf, oacc[t], 0, 0, 0);
      }
    }
    __syncthreads();
  }
  #pragma unroll
  for (int jj = 0; jj < 4; jj++){
    float inv = 1.f / l_run[jj];
    int q = qt * 64 + w * 16 + ((l >> 4) << 2) + jj;
    #pragma unroll
    for (int t = 0; t < 4; t++)
      Ob[(rb + q) * ldo + hoff + t * 16 + (l & 15)] = f2bf(oacc[t][jj] * inv);
  }
}

// ---------------- LayerNorm over D=1024 ----------------
__global__ __launch_bounds__(256)
void ln_kernel(const float* __restrict__ x1, const float* __restrict__ x2,
               const float* __restrict__ g, const float* __restrict__ be,
               float* __restrict__ outf, unsigned short* __restrict__ outb)
{
  const int row = blockIdx.x, t = threadIdx.x;
  __shared__ float red[4];
  const float4 v1 = ((const float4*)(x1 + (size_t)row * 1024))[t];
  const float4 v2 = ((const float4*)(x2 + (size_t)row * 1024))[t];
  float x[4] = {v1.x + v2.x, v1.y + v2.y, v1.z + v2.z, v1.w + v2.w};
  float s = x[0] + x[1] + x[2] + x[3];
  for (int o = 1; o < 64; o <<= 1) s += __shfl_xor(s, o);
  const int w = t >> 6, l = t & 63;
  if (l == 0) red[w] = s;
  __syncthreads();
  const float mean = (red[0] + red[1] + red[2] + red[3]) * (1.f / 1024.f);
  float d[4]; float sq = 0.f;
  #pragma unroll
  for (int i = 0; i < 4; i++){ d[i] = x[i] - mean; sq += d[i] * d[i]; }
  __syncthreads();
  for (int o = 1; o < 64; o <<= 1) sq += __shfl_xor(sq, o);
  if (l == 0) red[w] = sq;
  __syncthreads();
  const float var = (red[0] + red[1] + red[2] + red[3]) * (1.f / 1024.f);
  const float inv = rsqrtf(var + 1e-5f);
  const int base = t * 4;
  #pragma unroll
  for (int i = 0; i < 4; i++){
    float o = d[i] * inv * g[base + i] + be[base + i];
    if (outf) outf[(size_t)row * 1024 + base + i] = o;
    outb[(size_t)row * 1024 + base + i] = f2bf(o);
  }
}

// ---------------- x0 = dec + positional encoding ----------------
__global__ __launch_bounds__(256)
void build_x0(const float* __restrict__ dec, float* __restrict__ xf, unsigned short* __restrict__ xb)
{
  const int i = blockIdx.x * 256 + threadIdx.x;
  const int i4 = i * 4;
  const int d0 = i4 & 1023;
  const int s  = (i4 >> 10) & 1023;
  float4 dv = ((const float4*)dec)[i];
  const float* dvp = (const float*)&dv;
  float o[4];
  #pragma unroll
  for (int j = 0; j < 4; j++){
    int dd = d0 + j;
    float e = (float)(dd & ~1) * (1.f / 1024.f);
    float den = expf(e * 9.210340371976184f);
    float ang = (float)s / den;
    float pe = (dd & 1) ? cosf(ang) : sinf(ang);
    o[j] = dvp[j] + pe;
  }
  ((float4*)xf)[i] = make_float4(o[0], o[1], o[2], o[3]);
  ushort4v ob; ob[0] = f2bf(o[0]); ob[1] = f2bf(o[1]); ob[2] = f2bf(o[2]); ob[3] = f2bf(o[3]);
  ((ushort4v*)xb)[i] = ob;
}

__global__ __launch_bounds__(256)
void cvt_bf16_k(const float* __restrict__ in, unsigned short* __restrict__ out)
{
  const int i = blockIdx.x * 256 + threadIdx.x;
  float4 v = ((const float4*)in)[i];
  ushort4v o; o[0] = f2bf(v.x); o[1] = f2bf(v.y); o[2] = f2bf(v.z); o[3] = f2bf(v.w);
  ((ushort4v*)out)[i] = o;
}

// ---------------- transpose + convert ----------------
__global__ __launch_bounds__(256)
void transpose_cvt(const float* __restrict__ in, unsigned short* __restrict__ out, int R, int C)
{
  __shared__ float t[32][33];
  const int cb = blockIdx.x * 32, rbk = blockIdx.y * 32;
  const int tx = threadIdx.x & 31, ty = threadIdx.x >> 5;
  #pragma unroll
  for (int i = 0; i < 4; i++)
    t[ty + 8 * i][tx] = in[(size_t)(rbk + ty + 8 * i) * C + cb + tx];
  __syncthreads();
  #pragma unroll
  for (int i = 0; i < 4; i++){
    int c = ty + 8 * i;
    out[(size_t)(cb + c) * R + rbk + tx] = f2bf(t[tx][c]);
  }
}

struct TPtrs { const float* src[8]; unsigned short* dst[8]; };
__global__ __launch_bounds__(256)
void transpose_cvt8(TPtrs p)
{
  __shared__ float t[32][33];
  const float* __restrict__ in = p.src[blockIdx.z];
  unsigned short* __restrict__ out = p.dst[blockIdx.z];
  const int cb = blockIdx.x * 32, rbk = blockIdx.y * 32;
  const int tx = threadIdx.x & 31, ty = threadIdx.x >> 5;
  #pragma unroll
  for (int i = 0; i < 4; i++)
    t[ty + 8 * i][tx] = in[(size_t)(rbk + ty + 8 * i) * 1024 + cb + tx];
  __syncthreads();
  #pragma unroll
  for (int i = 0; i < 4; i++){
    int c = ty + 8 * i;
    out[(size_t)(cb + c) * 1024 + rbk + tx] = f2bf(t[tx][c]);
  }
}

__global__ __launch_bounds__(256)
void copy_biases(const float* sbq, const float* sbk, const float* sbv,
                 const float* cbk, const float* cbv,
                 float* bqkv, float* bkvc)
{
  const int i = blockIdx.x * 256 + threadIdx.x;
  const int seg = i >> 10, off = i & 1023;
  if (seg == 0)      bqkv[off] = sbq[off];
  else if (seg == 1) bqkv[1024 + off] = sbk[off];
  else if (seg == 2) bqkv[2048 + off] = sbv[off];
  else if (seg == 3) bkvc[off] = cbk[off];
  else               bkvc[1024 + off] = cbv[off];
}

extern "C" void kernel_launch(void* const* d_in, const int* in_sizes, int n_in,
                              void* d_out, int out_size, void* d_ws, size_t ws_size,
                              hipStream_t stream)
{
  constexpr int S = 1024, D = 1024, V = 32000, DF = 4096;
  constexpr int M = 2 * S;
  constexpr int DD = D * D;
  constexpr int l3 = 3;

  const float* dec  = (const float*)d_in[0];
  const float* enc  = (const float*)d_in[1];
  const float* sWq = (const float*)d_in[5]  + l3 * DD;
  const float* sWk = (const float*)d_in[6]  + l3 * DD;
  const float* sWv = (const float*)d_in[7]  + l3 * DD;
  const float* sWo = (const float*)d_in[8]  + l3 * DD;
  const float* cWq = (const float*)d_in[9]  + l3 * DD;
  const float* cWk = (const float*)d_in[10] + l3 * DD;
  const float* cWv = (const float*)d_in[11] + l3 * DD;
  const float* cWo = (const float*)d_in[12] + l3 * DD;
  const float* sbq = (const float*)d_in[13] + l3 * D;
  const float* sbk = (const float*)d_in[14] + l3 * D;
  const float* sbv = (const float*)d_in[15] + l3 * D;
  const float* sbo = (const float*)d_in[16] + l3 * D;
  const float* cbq = (const float*)d_in[17] + l3 * D;
  const float* cbk = (const float*)d_in[18] + l3 * D;
  const float* cbv = (const float*)d_in[19] + l3 * D;
  const float* cbo = (const float*)d_in[20] + l3 * D;
  const float* ln1g = (const float*)d_in[21] + l3 * D;
  const float* ln2g = (const float*)d_in[22] + l3 * D;
  const float* ln3g = (const float*)d_in[23] + l3 * D;
  const float* ln1b = (const float*)d_in[24] + l3 * D;
  const float* ln2b = (const float*)d_in[25] + l3 * D;
  const float* ln3b = (const float*)d_in[26] + l3 * D;
  const float* fW1 = (const float*)d_in[27] + (size_t)l3 * D * DF;
  const float* fb1 = (const float*)d_in[28] + l3 * DF;
  const float* fW2 = (const float*)d_in[29] + (size_t)l3 * DF * D;
  const float* fb2 = (const float*)d_in[30] + l3 * D;
  const float* Wout = (const float*)d_in[31];
  const float* bout = (const float*)d_in[32];
  float* out = (float*)d_out;

  uint8_t* wsp = (uint8_t*)d_ws;
  auto alloc = [&](size_t bytes) -> void* {
    void* p = wsp; wsp += (bytes + 255) & ~(size_t)255; return p;
  };
  float*          x0f  = (float*)alloc((size_t)M * D * 4);
  unsigned short* x0b  = (unsigned short*)alloc((size_t)M * D * 2);
  unsigned short* encb = (unsigned short*)alloc((size_t)M * D * 2);
  unsigned short* wqkv = (unsigned short*)alloc((size_t)3 * DD * 2);
  unsigned short* wos  = (unsigned short*)alloc((size_t)DD * 2);
  unsigned short* wqc  = (unsigned short*)alloc((size_t)DD * 2);
  unsigned short* wkvc = (unsigned short*)alloc((size_t)2 * DD * 2);
  unsigned short* woc  = (unsigned short*)alloc((size_t)DD * 2);
  unsigned short* wf1  = (unsigned short*)alloc((size_t)D * DF * 2);
  unsigned short* wf2  = (unsigned short*)alloc((size_t)D * DF * 2);
  unsigned short* wvo  = (unsigned short*)alloc((size_t)V * D * 2);
  float*          bqkv = (float*)alloc(3 * D * 4);
  float*          bkvc = (float*)alloc(2 * D * 4);
  unsigned short* qkv  = (unsigned short*)alloc((size_t)M * 3 * D * 2);
  unsigned short* attnb= (unsigned short*)alloc((size_t)M * D * 2);
  float*          oproj= (float*)alloc((size_t)M * D * 4);
  float*          a1f  = (float*)alloc((size_t)M * D * 4);
  unsigned short* a1b  = (unsigned short*)alloc((size_t)M * D * 2);
  unsigned short* qc   = (unsigned short*)alloc((size_t)M * D * 2);
  unsigned short* kvc  = (unsigned short*)alloc((size_t)M * 2 * D * 2);
  float*          a2f  = (float*)alloc((size_t)M * D * 4);
  unsigned short* a2b  = (unsigned short*)alloc((size_t)M * D * 2);
  unsigned short* ffh  = (unsigned short*)alloc((size_t)M * DF * 2);
  unsigned short* yb   = (unsigned short*)alloc((size_t)M * D * 2);

  build_x0<<<M * D / 4 / 256, 256, 0, stream>>>(dec, x0f, x0b);
  cvt_bf16_k<<<M * D / 4 / 256, 256, 0, stream>>>(enc, encb);

  TPtrs tp;
  tp.src[0] = sWq; tp.dst[0] = wqkv;
  tp.src[1] = sWk; tp.dst[1] = wqkv + DD;
  tp.src[2] = sWv; tp.dst[2] = wqkv + 2 * DD;
  tp.src[3] = sWo; tp.dst[3] = wos;
  tp.src[4] = cWq; tp.dst[4] = wqc;
  tp.src[5] = cWk; tp.dst[5] = wkvc;
  tp.src[6] = cWv; tp.dst[6] = wkvc + DD;
  tp.src[7] = cWo; tp.dst[7] = woc;
  transpose_cvt8<<<dim3(32, 32, 8), 256, 0, stream>>>(tp);
  transpose_cvt<<<dim3(DF/32, D/32), 256, 0, stream>>>(fW1, wf1, D, DF);
  transpose_cvt<<<dim3(D/32, DF/32), 256, 0, stream>>>(fW2, wf2, DF, D);
  transpose_cvt<<<dim3(V/32, D/32), 256, 0, stream>>>(Wout, wvo, D, V);
  copy_biases<<<20, 256, 0, stream>>>(sbq, sbk, sbv, cbk, cbv, bqkv, bkvc);

  // 3. self-attention block
  gemm128p<1><<<(M/128)*(3*D/128), 512, 0, stream>>>(x0b, wqkv, bqkv, qkv, M, 3*D, D);
  attn_kernel<1><<<dim3(S/64, 32), 256, 0, stream>>>(qkv, 3*D, qkv + D, 3*D, qkv + 2*D, 3*D, attnb, D);
  gemm_bt<64,64,0><<<(M/64)*(D/64), 256, 0, stream>>>(attnb, wos, sbo, oproj, M, D, D);
  ln_kernel<<<M, 256, 0, stream>>>(x0f, oproj, ln1g, ln1b, a1f, a1b);

  // 4. cross-attention block
  gemm_bt<64,64,1><<<(M/64)*(D/64), 256, 0, stream>>>(a1b, wqc, cbq, qc, M, D, D);
  gemm128p<1><<<(M/128)*(2*D/128), 512, 0, stream>>>(encb, wkvc, bkvc, kvc, M, 2*D, D);
  attn_kernel<0><<<dim3(S/64, 32), 256, 0, stream>>>(qc, D, kvc, 2*D, kvc + D, 2*D, attnb, D);
  gemm_bt<64,64,0><<<(M/64)*(D/64), 256, 0, stream>>>(attnb, woc, cbo, oproj, M, D, D);
  ln_kernel<<<M, 256, 0, stream>>>(a1f, oproj, ln2g, ln2b, a2f, a2b);

  // 5. FFN
  gemm128p<2><<<(M/128)*(DF/128), 512, 0, stream>>>(a2b, wf1, fb1, ffh, M, DF, D);
  gemm_bt<64,128,0><<<(M/64)*(D/128), 256, 0, stream>>>(ffh, wf2, fb2, oproj, M, D, DF);
  ln_kernel<<<M, 256, 0, stream>>>(a2f, oproj, ln3g, ln3b, nullptr, yb);

  // 6. logits
  gemm128p<3><<<(M/128)*(V/128), 512, 0, stream>>>(yb, wvo, bout, out, M, V, D);
}

// Round 6
// 623.668 us; speedup vs baseline: 1.0381x; 1.0381x over previous
//
#include <hip/hip_runtime.h>
#include <cstdint>
#include <cstddef>

#define DEV __device__ __forceinline__

typedef __attribute__((ext_vector_type(8))) short short8;
typedef __attribute__((ext_vector_type(4))) float f32x4;
typedef __attribute__((ext_vector_type(16))) float f32x16;
typedef __attribute__((ext_vector_type(4))) unsigned short ushort4v;

DEV unsigned short f2bf(float f){
  union { float f; unsigned int i; } v; v.f = f;
  unsigned int r = v.i + 0x7fffu + ((v.i >> 16) & 1u);
  return (unsigned short)(r >> 16);
}

DEV void gld_lds16(const unsigned short* g, unsigned short* lds){
  __builtin_amdgcn_global_load_lds((const __attribute__((address_space(1))) void*)g,
                                   (__attribute__((address_space(3))) void*)lds, 16, 0, 0);
}

// =================== 128xBN 4-wave GEMM on 32x32x16 MFMA, 3-buffer pipeline ===================
// C[M,N] = A[M,K](bf16) @ Bt[N,K]^T(bf16) + bias.  BK=32 (rows of 64B = 4 slots x 16B),
// slot swizzle phys = logical ^ (row&3), staged via pre-swizzled global k-offset (rule #21).
// Wave tile 64 x BN/2: acc f32x16[2][BN/64].  FLOP per LDS byte = 2x the 16x16 shape ->
// flips the kernel from LDS-read-BW-bound (the r3-r5 27% MfmaUtil wall) to MFMA-bound.
// Pipeline: buffer u%3 read at tile u; stages for tile u+2 issued during tile u into
// buffer (u+2)%3 (= buffer retired at end of tile u-1).  ONE barrier + one counted
// vmcnt(GLD) per tile; tile u+1's loads (older than this tile's GLD issues) are
// guaranteed complete by the wait.  vmcnt(0) only at u==nk-2.
template<int BN, int EPI>
__global__ __launch_bounds__(256, 2)
void gemm32(const unsigned short* __restrict__ A,
            const unsigned short* __restrict__ Bt,
            const float* __restrict__ bias,
            void* __restrict__ C, int M, int N, int K)
{
  constexpr int NFR  = BN / 64;          // B frags per wave (2 or 4)
  constexpr int ROWS = 128 + BN;
  constexpr int BUFH = ROWS * 32;        // halves per buffer
  constexpr int GLD  = ROWS / 64;        // global_load_lds per tile (4 or 6)
  __shared__ __align__(16) unsigned short lds[3 * BUFH];

  const int tid = threadIdx.x, wid = tid >> 6, l = tid & 63;
  const int wr = wid >> 1, wcn = wid & 1;

  const int nbm = M / 128, nbn = N / BN;
  const int nwg = nbm * nbn;
  const int q8 = nwg >> 3, r8 = nwg & 7;
  const int xcd = blockIdx.x & 7, within = blockIdx.x >> 3;
  const int wg = (xcd < r8 ? xcd * (q8 + 1) : r8 * (q8 + 1) + (xcd - r8) * q8) + within;
  const int mb = (wg % nbm) * 128, nb = (wg / nbm) * BN;

  const int nk = K / 32;

  const int r31 = l & 31, hi = l >> 5;
  const int so0 = (( hi)      ^ (r31 & 3)) * 8;   // ks=0 slot byte-offset (halves)
  const int so1 = ((2 + hi)   ^ (r31 & 3)) * 8;   // ks=1
  const int abase = (wr * 64 + r31) * 32;
  const int bbase = 4096 + (wcn * (BN / 2) + r31) * 32;

  f32x16 acc[2][NFR];
  #pragma unroll
  for (int m = 0; m < 2; m++)
    #pragma unroll
    for (int n = 0; n < NFR; n++)
      #pragma unroll
      for (int e = 0; e < 16; e++) acc[m][n][e] = 0.f;

#define STAGE_A(c, tt, bb) \
  gld_lds16(A + (size_t)(mb + (c)*64 + (tid>>2)) * K + (size_t)(tt)*32 + (((tid&3)^((tid>>2)&3))*8), \
            lds + (bb)*BUFH + (c)*2048 + tid*8)
#define STAGE_B(c, tt, bb) \
  gld_lds16(Bt + (size_t)(nb + (c)*64 + (tid>>2)) * K + (size_t)(tt)*32 + (((tid&3)^((tid>>2)&3))*8), \
            lds + (bb)*BUFH + 4096 + (c)*2048 + tid*8)
#define WAIT_GLD() do { if constexpr (GLD == 6) asm volatile("s_waitcnt vmcnt(6)" ::: "memory"); \
                        else                    asm volatile("s_waitcnt vmcnt(4)" ::: "memory"); } while(0)

  // prologue: tile0 -> buf0, tile1 -> buf1
  STAGE_A(0, 0, 0); STAGE_A(1, 0, 0);
  #pragma unroll
  for (int c = 0; c < NFR; c++) STAGE_B(c, 0, 0);
  if (nk > 1){
    STAGE_A(0, 1, 1); STAGE_A(1, 1, 1);
    #pragma unroll
    for (int c = 0; c < NFR; c++) STAGE_B(c, 1, 1);
    WAIT_GLD();
  } else {
    asm volatile("s_waitcnt vmcnt(0)" ::: "memory");
  }
  asm volatile("" ::: "memory");
  __builtin_amdgcn_s_barrier();
  asm volatile("" ::: "memory");

  int bb = 0;
  for (int u = 0; u < nk; u++){
    const unsigned short* buf = lds + bb * BUFH;
    const int sb = (bb >= 1) ? bb - 1 : 2;      // (bb+2)%3
    const bool st = (u + 2 < nk);
    short8 af[2], bf[NFR];

    // ---- kstep 0 ----
    af[0] = *(const short8*)(buf + abase + so0);
    af[1] = *(const short8*)(buf + abase + 1024 + so0);
    #pragma unroll
    for (int n = 0; n < NFR; n++) bf[n] = *(const short8*)(buf + bbase + n * 1024 + so0);
    if (st){
      STAGE_A(0, u + 2, sb); STAGE_A(1, u + 2, sb);
      if constexpr (NFR == 4) STAGE_B(0, u + 2, sb);
    }
    __builtin_amdgcn_s_setprio(1);
    #pragma unroll
    for (int m = 0; m < 2; m++)
      #pragma unroll
      for (int n = 0; n < NFR; n++)
        acc[m][n] = __builtin_amdgcn_mfma_f32_32x32x16_bf16(af[m], bf[n], acc[m][n], 0, 0, 0);
    __builtin_amdgcn_s_setprio(0);

    // ---- kstep 1 ----
    af[0] = *(const short8*)(buf + abase + so1);
    af[1] = *(const short8*)(buf + abase + 1024 + so1);
    #pragma unroll
    for (int n = 0; n < NFR; n++) bf[n] = *(const short8*)(buf + bbase + n * 1024 + so1);
    if (st){
      if constexpr (NFR == 4){ STAGE_B(1, u + 2, sb); STAGE_B(2, u + 2, sb); STAGE_B(3, u + 2, sb); }
      else                   { STAGE_B(0, u + 2, sb); STAGE_B(1, u + 2, sb); }
    }
    __builtin_amdgcn_s_setprio(1);
    #pragma unroll
    for (int m = 0; m < 2; m++)
      #pragma unroll
      for (int n = 0; n < NFR; n++)
        acc[m][n] = __builtin_amdgcn_mfma_f32_32x32x16_bf16(af[m], bf[n], acc[m][n], 0, 0, 0);
    __builtin_amdgcn_s_setprio(0);

    if (st)               WAIT_GLD();
    else if (u + 1 < nk)  asm volatile("s_waitcnt vmcnt(0)" ::: "memory");
    asm volatile("" ::: "memory");
    __builtin_amdgcn_s_barrier();
    asm volatile("" ::: "memory");
    bb = (bb == 2) ? 0 : bb + 1;
  }
#undef WAIT_GLD
#undef STAGE_A
#undef STAGE_B

  // epilogue: col = lane&31, row = (reg&3) + 8*(reg>>2) + 4*hi  [m74/m101]
  #pragma unroll
  for (int n = 0; n < NFR; n++){
    const int col = nb + wcn * (BN / 2) + n * 32 + r31;
    const float bv = bias ? bias[col] : 0.f;
    #pragma unroll
    for (int m = 0; m < 2; m++){
      const int rowb = mb + wr * 64 + m * 32 + 4 * hi;
      #pragma unroll
      for (int reg = 0; reg < 16; reg++){
        const int row = rowb + (reg & 3) + 8 * (reg >> 2);
        float v = acc[m][n][reg] + bv;
        size_t idx = (size_t)row * N + col;
        if (EPI == 0)       ((float*)C)[idx] = v;
        else if (EPI == 3)  __builtin_nontemporal_store(v, &((float*)C)[idx]);
        else if (EPI == 1)  ((unsigned short*)C)[idx] = f2bf(v);
        else { v = v > 0.f ? v : 0.f; ((unsigned short*)C)[idx] = f2bf(v); }
      }
    }
  }
}

// ---------------- GEMM (m97-style 2-phase): C[M,N] = A@Bt^T + bias ----------------
template<int BM, int BN, int EPI>
__global__ __launch_bounds__(256, 2)
void gemm_bt(const unsigned short* __restrict__ A,
             const unsigned short* __restrict__ Bt,
             const float* __restrict__ bias,
             void* __restrict__ C, int M, int N, int K)
{
  constexpr int MF = BM / 32, NF = BN / 32;
  constexpr int LA = BM / 64, LB = BN / 64;
  __shared__ __align__(16) unsigned short lds[2 * (BM + BN) * 32];

  const int tid = threadIdx.x, w = tid >> 6, l = tid & 63;
  const int wr = w >> 1, wc = w & 1;

  const int nbm = M / BM, nbn = N / BN;
  const int nwg = nbm * nbn;
  const int q8 = nwg >> 3, r8 = nwg & 7;
  const int xcd = blockIdx.x & 7, within = blockIdx.x >> 3;
  const int wg = (xcd < r8 ? xcd * (q8 + 1) : r8 * (q8 + 1) + (xcd - r8) * q8) + within;
  const int mb = (wg % nbm) * BM, nb = (wg / nbm) * BN;

  unsigned short* As0 = lds;
  unsigned short* Bs0 = lds + BM * 32;
  unsigned short* As1 = lds + (BM + BN) * 32;
  unsigned short* Bs1 = As1 + BM * 32;

  f32x4 acc[MF][NF];
  #pragma unroll
  for (int m = 0; m < MF; m++)
    #pragma unroll
    for (int n = 0; n < NF; n++) acc[m][n] = (f32x4){0.f, 0.f, 0.f, 0.f};

  const int srow = l >> 2;
  const int scol = (((l & 3) ^ ((l >> 2) & 3) ^ ((l >> 4) & 3)) * 8);
  const int rswz = (l & 3) ^ ((l >> 2) & 3);

  #define STAGE(Ad, Bd, k0) do { \
    _Pragma("unroll") \
    for (int i = 0; i < LA; i++){ \
      int chunk = i * 4 + w; \
      gld_lds16(A + (size_t)(mb + chunk * 16 + srow) * K + (k0) + scol, (Ad) + chunk * 512); \
    } \
    _Pragma("unroll") \
    for (int i = 0; i < LB; i++){ \
      int chunk = i * 4 + w; \
      gld_lds16(Bt + (size_t)(nb + chunk * 16 + srow) * K + (k0) + scol, (Bd) + chunk * 512); \
    } } while(0)

  STAGE(As0, Bs0, 0);
  const int nk = K / 32;
  const int rdoff = ((l >> 4) ^ rswz) * 8;
  for (int kt = 0; kt < nk; kt++){
    __syncthreads();
    unsigned short* Ac = (kt & 1) ? As1 : As0;
    unsigned short* Bc = (kt & 1) ? Bs1 : Bs0;
    if (kt + 1 < nk){
      unsigned short* An = (kt & 1) ? As0 : As1;
      unsigned short* Bn = (kt & 1) ? Bs0 : Bs1;
      STAGE(An, Bn, (kt + 1) * 32);
    }
    short8 af[MF], bfr[NF];
    #pragma unroll
    for (int m = 0; m < MF; m++)
      af[m] = *(const short8*)(Ac + (wr * (BM / 2) + m * 16 + (l & 15)) * 32 + rdoff);
    #pragma unroll
    for (int n = 0; n < NF; n++)
      bfr[n] = *(const short8*)(Bc + (wc * (BN / 2) + n * 16 + (l & 15)) * 32 + rdoff);
    #pragma unroll
    for (int m = 0; m < MF; m++)
      #pragma unroll
      for (int n = 0; n < NF; n++)
        acc[m][n] = __builtin_amdgcn_mfma_f32_16x16x32_bf16(af[m], bfr[n], acc[m][n], 0, 0, 0);
  }
  #undef STAGE

  #pragma unroll
  for (int n = 0; n < NF; n++){
    const int col = nb + wc * (BN / 2) + n * 16 + (l & 15);
    const float bv = bias ? bias[col] : 0.f;
    #pragma unroll
    for (int m = 0; m < MF; m++){
      const int row0 = mb + wr * (BM / 2) + m * 16 + ((l >> 4) << 2);
      #pragma unroll
      for (int jj = 0; jj < 4; jj++){
        float v = acc[m][n][jj] + bv;
        size_t idx = (size_t)(row0 + jj) * N + col;
        if (EPI == 0)       ((float*)C)[idx] = v;
        else if (EPI == 3)  __builtin_nontemporal_store(v, &((float*)C)[idx]);
        else if (EPI == 1)  ((unsigned short*)C)[idx] = f2bf(v);
        else { v = v > 0.f ? v : 0.f; ((unsigned short*)C)[idx] = f2bf(v); }
      }
    }
  }
}

// ---------------- Flash attention: 64 q-rows / block (4 waves x 16), dh=64, H=16 ----------------
template<int CAUSAL>
__global__ __launch_bounds__(256)
void attn_kernel(const unsigned short* __restrict__ Qb, int ldq,
                 const unsigned short* __restrict__ Kb, int ldk,
                 const unsigned short* __restrict__ Vb, int ldv,
                 unsigned short* __restrict__ Ob, int ldo)
{
  constexpr int S = 1024;
  __shared__ __align__(16) unsigned short vt[64][40];
  __shared__ __align__(16) unsigned short plds[4][16][40];
  const int tid = threadIdx.x, w = tid >> 6, l = tid & 63;
  const int qt = blockIdx.x, bh = blockIdx.y;
  const int b = bh >> 4, h = bh & 15;
  const int hoff = h * 64;
  const size_t rb = (size_t)b * S;

  const int qrow = qt * 64 + w * 16 + (l & 15);
  const unsigned short* qp = Qb + (rb + qrow) * ldq + hoff + ((l >> 4) * 8);
  short8 qf0 = *(const short8*)qp;
  short8 qf1 = *(const short8*)(qp + 32);

  float m_run[4] = {-1e30f, -1e30f, -1e30f, -1e30f};
  float l_run[4] = {0.f, 0.f, 0.f, 0.f};
  f32x4 oacc[4];
  #pragma unroll
  for (int t = 0; t < 4; t++) oacc[t] = (f32x4){0.f, 0.f, 0.f, 0.f};

  const int qmax = qt * 64 + w * 16 + 15;
  const int nkeys = CAUSAL ? (qt * 64 + 64) : S;
  const int skey = tid >> 3, sd8 = (tid & 7) * 8;

  for (int kb = 0; kb < nkeys; kb += 32){
    short8 vv = *(const short8*)(Vb + (rb + kb + skey) * ldv + hoff + sd8);
    #pragma unroll
    for (int i = 0; i < 8; i++) vt[sd8 + i][skey] = (unsigned short)vv[i];
    __syncthreads();
    if (!CAUSAL || kb <= qmax){
      f32x4 sc[2];
      #pragma unroll
      for (int g = 0; g < 2; g++){
        const unsigned short* kp = Kb + (rb + kb + g * 16 + (l & 15)) * ldk + hoff + ((l >> 4) * 8);
        short8 kf0 = *(const short8*)kp;
        short8 kf1 = *(const short8*)(kp + 32);
        f32x4 z = (f32x4){0.f, 0.f, 0.f, 0.f};
        z = __builtin_amdgcn_mfma_f32_16x16x32_bf16(qf0, kf0, z, 0, 0, 0);
        z = __builtin_amdgcn_mfma_f32_16x16x32_bf16(qf1, kf1, z, 0, 0, 0);
        sc[g] = z;
      }
      #pragma unroll
      for (int jj = 0; jj < 4; jj++){
        float s0 = sc[0][jj] * 0.125f, s1 = sc[1][jj] * 0.125f;
        if (CAUSAL){
          int q = qt * 64 + w * 16 + ((l >> 4) << 2) + jj;
          if (kb + (l & 15) > q)      s0 = -1e30f;
          if (kb + 16 + (l & 15) > q) s1 = -1e30f;
        }
        float mx = fmaxf(s0, s1);
        mx = fmaxf(mx, __shfl_xor(mx, 1));
        mx = fmaxf(mx, __shfl_xor(mx, 2));
        mx = fmaxf(mx, __shfl_xor(mx, 4));
        mx = fmaxf(mx, __shfl_xor(mx, 8));
        float mnew = fmaxf(m_run[jj], mx);
        float scal = __expf(m_run[jj] - mnew);
        m_run[jj] = mnew;
        float p0 = __expf(s0 - mnew), p1 = __expf(s1 - mnew);
        float rs = p0 + p1;
        rs += __shfl_xor(rs, 1); rs += __shfl_xor(rs, 2);
        rs += __shfl_xor(rs, 4); rs += __shfl_xor(rs, 8);
        l_run[jj] = l_run[jj] * scal + rs;
        #pragma unroll
        for (int t = 0; t < 4; t++) oacc[t][jj] *= scal;
        int qr = ((l >> 4) << 2) + jj;
        plds[w][qr][l & 15]      = f2bf(p0);
        plds[w][qr][16 + (l & 15)] = f2bf(p1);
      }
      asm volatile("s_waitcnt lgkmcnt(0)" ::: "memory");
      short8 pf = *(const short8*)&plds[w][l & 15][(l >> 4) * 8];
      #pragma unroll
      for (int t = 0; t < 4; t++){
        short8 vf = *(const short8*)&vt[t * 16 + (l & 15)][(l >> 4) * 8];
        oacc[t] = __builtin_amdgcn_mfma_f32_16x16x32_bf16(pf, vf, oacc[t], 0, 0, 0);
      }
    }
    __syncthreads();
  }
  #pragma unroll
  for (int jj = 0; jj < 4; jj++){
    float inv = 1.f / l_run[jj];
    int q = qt * 64 + w * 16 + ((l >> 4) << 2) + jj;
    #pragma unroll
    for (int t = 0; t < 4; t++)
      Ob[(rb + q) * ldo + hoff + t * 16 + (l & 15)] = f2bf(oacc[t][jj] * inv);
  }
}

// ---------------- LayerNorm over D=1024 ----------------
__global__ __launch_bounds__(256)
void ln_kernel(const float* __restrict__ x1, const float* __restrict__ x2,
               const float* __restrict__ g, const float* __restrict__ be,
               float* __restrict__ outf, unsigned short* __restrict__ outb)
{
  const int row = blockIdx.x, t = threadIdx.x;
  __shared__ float red[4];
  const float4 v1 = ((const float4*)(x1 + (size_t)row * 1024))[t];
  const float4 v2 = ((const float4*)(x2 + (size_t)row * 1024))[t];
  float x[4] = {v1.x + v2.x, v1.y + v2.y, v1.z + v2.z, v1.w + v2.w};
  float s = x[0] + x[1] + x[2] + x[3];
  for (int o = 1; o < 64; o <<= 1) s += __shfl_xor(s, o);
  const int w = t >> 6, l = t & 63;
  if (l == 0) red[w] = s;
  __syncthreads();
  const float mean = (red[0] + red[1] + red[2] + red[3]) * (1.f / 1024.f);
  float d[4]; float sq = 0.f;
  #pragma unroll
  for (int i = 0; i < 4; i++){ d[i] = x[i] - mean; sq += d[i] * d[i]; }
  __syncthreads();
  for (int o = 1; o < 64; o <<= 1) sq += __shfl_xor(sq, o);
  if (l == 0) red[w] = sq;
  __syncthreads();
  const float var = (red[0] + red[1] + red[2] + red[3]) * (1.f / 1024.f);
  const float inv = rsqrtf(var + 1e-5f);
  const int base = t * 4;
  #pragma unroll
  for (int i = 0; i < 4; i++){
    float o = d[i] * inv * g[base + i] + be[base + i];
    if (outf) outf[(size_t)row * 1024 + base + i] = o;
    outb[(size_t)row * 1024 + base + i] = f2bf(o);
  }
}

// ---------------- x0 = dec + positional encoding ----------------
__global__ __launch_bounds__(256)
void build_x0(const float* __restrict__ dec, float* __restrict__ xf, unsigned short* __restrict__ xb)
{
  const int i = blockIdx.x * 256 + threadIdx.x;
  const int i4 = i * 4;
  const int d0 = i4 & 1023;
  const int s  = (i4 >> 10) & 1023;
  float4 dv = ((const float4*)dec)[i];
  const float* dvp = (const float*)&dv;
  float o[4];
  #pragma unroll
  for (int j = 0; j < 4; j++){
    int dd = d0 + j;
    float e = (float)(dd & ~1) * (1.f / 1024.f);
    float den = expf(e * 9.210340371976184f);
    float ang = (float)s / den;
    float pe = (dd & 1) ? cosf(ang) : sinf(ang);
    o[j] = dvp[j] + pe;
  }
  ((float4*)xf)[i] = make_float4(o[0], o[1], o[2], o[3]);
  ushort4v ob; ob[0] = f2bf(o[0]); ob[1] = f2bf(o[1]); ob[2] = f2bf(o[2]); ob[3] = f2bf(o[3]);
  ((ushort4v*)xb)[i] = ob;
}

__global__ __launch_bounds__(256)
void cvt_bf16_k(const float* __restrict__ in, unsigned short* __restrict__ out)
{
  const int i = blockIdx.x * 256 + threadIdx.x;
  float4 v = ((const float4*)in)[i];
  ushort4v o; o[0] = f2bf(v.x); o[1] = f2bf(v.y); o[2] = f2bf(v.z); o[3] = f2bf(v.w);
  ((ushort4v*)out)[i] = o;
}

// ---------------- transpose + convert ----------------
__global__ __launch_bounds__(256)
void transpose_cvt(const float* __restrict__ in, unsigned short* __restrict__ out, int R, int C)
{
  __shared__ float t[32][33];
  const int cb = blockIdx.x * 32, rbk = blockIdx.y * 32;
  const int tx = threadIdx.x & 31, ty = threadIdx.x >> 5;
  #pragma unroll
  for (int i = 0; i < 4; i++)
    t[ty + 8 * i][tx] = in[(size_t)(rbk + ty + 8 * i) * C + cb + tx];
  __syncthreads();
  #pragma unroll
  for (int i = 0; i < 4; i++){
    int c = ty + 8 * i;
    out[(size_t)(cb + c) * R + rbk + tx] = f2bf(t[tx][c]);
  }
}

struct TPtrs { const float* src[8]; unsigned short* dst[8]; };
__global__ __launch_bounds__(256)
void transpose_cvt8(TPtrs p)
{
  __shared__ float t[32][33];
  const float* __restrict__ in = p.src[blockIdx.z];
  unsigned short* __restrict__ out = p.dst[blockIdx.z];
  const int cb = blockIdx.x * 32, rbk = blockIdx.y * 32;
  const int tx = threadIdx.x & 31, ty = threadIdx.x >> 5;
  #pragma unroll
  for (int i = 0; i < 4; i++)
    t[ty + 8 * i][tx] = in[(size_t)(rbk + ty + 8 * i) * 1024 + cb + tx];
  __syncthreads();
  #pragma unroll
  for (int i = 0; i < 4; i++){
    int c = ty + 8 * i;
    out[(size_t)(cb + c) * 1024 + rbk + tx] = f2bf(t[tx][c]);
  }
}

__global__ __launch_bounds__(256)
void copy_biases(const float* sbq, const float* sbk, const float* sbv,
                 const float* cbk, const float* cbv,
                 float* bqkv, float* bkvc)
{
  const int i = blockIdx.x * 256 + threadIdx.x;
  const int seg = i >> 10, off = i & 1023;
  if (seg == 0)      bqkv[off] = sbq[off];
  else if (seg == 1) bqkv[1024 + off] = sbk[off];
  else if (seg == 2) bqkv[2048 + off] = sbv[off];
  else if (seg == 3) bkvc[off] = cbk[off];
  else               bkvc[1024 + off] = cbv[off];
}

extern "C" void kernel_launch(void* const* d_in, const int* in_sizes, int n_in,
                              void* d_out, int out_size, void* d_ws, size_t ws_size,
                              hipStream_t stream)
{
  constexpr int S = 1024, D = 1024, V = 32000, DF = 4096;
  constexpr int M = 2 * S;
  constexpr int DD = D * D;
  constexpr int l3 = 3;

  const float* dec  = (const float*)d_in[0];
  const float* enc  = (const float*)d_in[1];
  const float* sWq = (const float*)d_in[5]  + l3 * DD;
  const float* sWk = (const float*)d_in[6]  + l3 * DD;
  const float* sWv = (const float*)d_in[7]  + l3 * DD;
  const float* sWo = (const float*)d_in[8]  + l3 * DD;
  const float* cWq = (const float*)d_in[9]  + l3 * DD;
  const float* cWk = (const float*)d_in[10] + l3 * DD;
  const float* cWv = (const float*)d_in[11] + l3 * DD;
  const float* cWo = (const float*)d_in[12] + l3 * DD;
  const float* sbq = (const float*)d_in[13] + l3 * D;
  const float* sbk = (const float*)d_in[14] + l3 * D;
  const float* sbv = (const float*)d_in[15] + l3 * D;
  const float* sbo = (const float*)d_in[16] + l3 * D;
  const float* cbq = (const float*)d_in[17] + l3 * D;
  const float* cbk = (const float*)d_in[18] + l3 * D;
  const float* cbv = (const float*)d_in[19] + l3 * D;
  const float* cbo = (const float*)d_in[20] + l3 * D;
  const float* ln1g = (const float*)d_in[21] + l3 * D;
  const float* ln2g = (const float*)d_in[22] + l3 * D;
  const float* ln3g = (const float*)d_in[23] + l3 * D;
  const float* ln1b = (const float*)d_in[24] + l3 * D;
  const float* ln2b = (const float*)d_in[25] + l3 * D;
  const float* ln3b = (const float*)d_in[26] + l3 * D;
  const float* fW1 = (const float*)d_in[27] + (size_t)l3 * D * DF;
  const float* fb1 = (const float*)d_in[28] + l3 * DF;
  const float* fW2 = (const float*)d_in[29] + (size_t)l3 * DF * D;
  const float* fb2 = (const float*)d_in[30] + l3 * D;
  const float* Wout = (const float*)d_in[31];
  const float* bout = (const float*)d_in[32];
  float* out = (float*)d_out;

  uint8_t* wsp = (uint8_t*)d_ws;
  auto alloc = [&](size_t bytes) -> void* {
    void* p = wsp; wsp += (bytes + 255) & ~(size_t)255; return p;
  };
  float*          x0f  = (float*)alloc((size_t)M * D * 4);
  unsigned short* x0b  = (unsigned short*)alloc((size_t)M * D * 2);
  unsigned short* encb = (unsigned short*)alloc((size_t)M * D * 2);
  unsigned short* wqkv = (unsigned short*)alloc((size_t)3 * DD * 2);
  unsigned short* wos  = (unsigned short*)alloc((size_t)DD * 2);
  unsigned short* wqc  = (unsigned short*)alloc((size_t)DD * 2);
  unsigned short* wkvc = (unsigned short*)alloc((size_t)2 * DD * 2);
  unsigned short* woc  = (unsigned short*)alloc((size_t)DD * 2);
  unsigned short* wf1  = (unsigned short*)alloc((size_t)D * DF * 2);
  unsigned short* wf2  = (unsigned short*)alloc((size_t)D * DF * 2);
  unsigned short* wvo  = (unsigned short*)alloc((size_t)V * D * 2);
  float*          bqkv = (float*)alloc(3 * D * 4);
  float*          bkvc = (float*)alloc(2 * D * 4);
  unsigned short* qkv  = (unsigned short*)alloc((size_t)M * 3 * D * 2);
  unsigned short* attnb= (unsigned short*)alloc((size_t)M * D * 2);
  float*          oproj= (float*)alloc((size_t)M * D * 4);
  float*          a1f  = (float*)alloc((size_t)M * D * 4);
  unsigned short* a1b  = (unsigned short*)alloc((size_t)M * D * 2);
  unsigned short* qc   = (unsigned short*)alloc((size_t)M * D * 2);
  unsigned short* kvc  = (unsigned short*)alloc((size_t)M * 2 * D * 2);
  float*          a2f  = (float*)alloc((size_t)M * D * 4);
  unsigned short* a2b  = (unsigned short*)alloc((size_t)M * D * 2);
  unsigned short* ffh  = (unsigned short*)alloc((size_t)M * DF * 2);
  unsigned short* yb   = (unsigned short*)alloc((size_t)M * D * 2);

  build_x0<<<M * D / 4 / 256, 256, 0, stream>>>(dec, x0f, x0b);
  cvt_bf16_k<<<M * D / 4 / 256, 256, 0, stream>>>(enc, encb);

  TPtrs tp;
  tp.src[0] = sWq; tp.dst[0] = wqkv;
  tp.src[1] = sWk; tp.dst[1] = wqkv + DD;
  tp.src[2] = sWv; tp.dst[2] = wqkv + 2 * DD;
  tp.src[3] = sWo; tp.dst[3] = wos;
  tp.src[4] = cWq; tp.dst[4] = wqc;
  tp.src[5] = cWk; tp.dst[5] = wkvc;
  tp.src[6] = cWv; tp.dst[6] = wkvc + DD;
  tp.src[7] = cWo; tp.dst[7] = woc;
  transpose_cvt8<<<dim3(32, 32, 8), 256, 0, stream>>>(tp);
  transpose_cvt<<<dim3(DF/32, D/32), 256, 0, stream>>>(fW1, wf1, D, DF);
  transpose_cvt<<<dim3(D/32, DF/32), 256, 0, stream>>>(fW2, wf2, DF, D);
  transpose_cvt<<<dim3(V/32, D/32), 256, 0, stream>>>(Wout, wvo, D, V);
  copy_biases<<<20, 256, 0, stream>>>(sbq, sbk, sbv, cbk, cbv, bqkv, bkvc);

  // 3. self-attention block
  gemm32<128,1><<<(M/128)*(3*D/128), 256, 0, stream>>>(x0b, wqkv, bqkv, qkv, M, 3*D, D);
  attn_kernel<1><<<dim3(S/64, 32), 256, 0, stream>>>(qkv, 3*D, qkv + D, 3*D, qkv + 2*D, 3*D, attnb, D);
  gemm_bt<64,64,0><<<(M/64)*(D/64), 256, 0, stream>>>(attnb, wos, sbo, oproj, M, D, D);
  ln_kernel<<<M, 256, 0, stream>>>(x0f, oproj, ln1g, ln1b, a1f, a1b);

  // 4. cross-attention block
  gemm_bt<64,64,1><<<(M/64)*(D/64), 256, 0, stream>>>(a1b, wqc, cbq, qc, M, D, D);
  gemm32<128,1><<<(M/128)*(2*D/128), 256, 0, stream>>>(encb, wkvc, bkvc, kvc, M, 2*D, D);
  attn_kernel<0><<<dim3(S/64, 32), 256, 0, stream>>>(qc, D, kvc, 2*D, kvc + D, 2*D, attnb, D);
  gemm_bt<64,64,0><<<(M/64)*(D/64), 256, 0, stream>>>(attnb, woc, cbo, oproj, M, D, D);
  ln_kernel<<<M, 256, 0, stream>>>(a1f, oproj, ln2g, ln2b, a2f, a2b);

  // 5. FFN
  gemm32<128,2><<<(M/128)*(DF/128), 256, 0, stream>>>(a2b, wf1, fb1, ffh, M, DF, D);
  gemm_bt<64,128,0><<<(M/64)*(D/128), 256, 0, stream>>>(ffh, wf2, fb2, oproj, M, D, DF);
  ln_kernel<<<M, 256, 0, stream>>>(a2f, oproj, ln3g, ln3b, nullptr, yb);

  // 6. logits
  gemm32<256,3><<<(M/128)*(V/256), 256, 0, stream>>>(yb, wvo, bout, out, M, V, D);
}

// Round 7
// 603.619 us; speedup vs baseline: 1.0726x; 1.0332x over previous
//
#include <hip/hip_runtime.h>
#include <cstdint>
#include <cstddef>

#define DEV __device__ __forceinline__

typedef __attribute__((ext_vector_type(8))) short short8;
typedef __attribute__((ext_vector_type(4))) float f32x4;
typedef __attribute__((ext_vector_type(16))) float f32x16;
typedef __attribute__((ext_vector_type(4))) unsigned short ushort4v;

DEV unsigned short f2bf(float f){
  union { float f; unsigned int i; } v; v.f = f;
  unsigned int r = v.i + 0x7fffu + ((v.i >> 16) & 1u);
  return (unsigned short)(r >> 16);
}

DEV void gld_lds16(const unsigned short* g, unsigned short* lds){
  __builtin_amdgcn_global_load_lds((const __attribute__((address_space(1))) void*)g,
                                   (__attribute__((address_space(3))) void*)lds, 16, 0, 0);
}

// swizzled offset (halves) of (row r, k-slot s) within a 64-row chunk.
// Layout: two 64B rows per 128B line; 8 slots/line; phys = sl ^ (line&7).
// Bank proof: quarter-wave lanes 0-15 read rows 0-15 at fixed s -> phys hits each
// 16B slot exactly twice (2-way = free, m136). Rows 16-31 identical pattern.
DEV int swz(int r, int s){
  int ln = r >> 1;
  int sl = ((r & 1) << 2) | s;
  return ln * 64 + (((sl ^ (ln & 7))) << 3);
}

// =================== 128xBN 4-wave GEMM on 32x32x16 MFMA, 3-buffer pipeline ===================
// C[M,N] = A[M,K](bf16) @ Bt[N,K]^T(bf16) + bias.  BK=32; chunks of 64 rows (4KB).
// Buffer u%3 read at tile u; stages for u+2 issued during u into buffer (u+2)%3
// (retired at end of tile u-1). ONE barrier + counted vmcnt(GLD) per tile (0 only at
// nk-2). Staging (rule #21): thread t writes LDS linearly at t*16B = line(t>>3), phys(t&7);
// its GLOBAL source is the logical slot sl=(t&7)^(line&7): row=2*line+(sl>>2), kcol=(sl&3)*8.
template<int BN, int EPI>
__global__ __launch_bounds__(256, 2)
void gemm32(const unsigned short* __restrict__ A,
            const unsigned short* __restrict__ Bt,
            const float* __restrict__ bias,
            void* __restrict__ C, int M, int N, int K)
{
  constexpr int NFR  = BN / 64;          // B frags per wave (1, 2 or 4)
  constexpr int ROWS = 128 + BN;
  constexpr int BUFH = ROWS * 32;        // halves per buffer
  constexpr int GLD  = ROWS / 64;        // global_load_lds per tile (3, 4 or 6)
  __shared__ __align__(16) unsigned short lds[3 * BUFH];

  const int tid = threadIdx.x, wid = tid >> 6, l = tid & 63;
  const int wr = wid >> 1, wcn = wid & 1;

  const int nbm = M / 128, nbn = N / BN;
  const int nwg = nbm * nbn;
  const int q8 = nwg >> 3, r8 = nwg & 7;
  const int xcd = blockIdx.x & 7, within = blockIdx.x >> 3;
  const int wg = (xcd < r8 ? xcd * (q8 + 1) : r8 * (q8 + 1) + (xcd - r8) * q8) + within;
  const int mb = (wg % nbm) * 128, nb = (wg / nbm) * BN;

  const int nk = K / 32;

  // staging source coordinates (chunk-relative)
  const int sL   = tid >> 3;
  const int sSl  = (tid & 7) ^ (sL & 7);
  const int sRow = sL * 2 + (sSl >> 2);
  const int sKc  = (sSl & 3) * 8;

  const int r31 = l & 31, hi = l >> 5;

  // per-thread read offsets (halves): A region = chunks 0..1 (4096 halves), B after.
  int aoff[2][2], boff[NFR][2];
  #pragma unroll
  for (int m = 0; m < 2; m++)
    #pragma unroll
    for (int ks = 0; ks < 2; ks++)
      aoff[m][ks] = wr * 2048 + swz(m * 32 + r31, 2 * ks + hi);
  #pragma unroll
  for (int n = 0; n < NFR; n++){
    const int col = wcn * (BN / 2) + n * 32 + r31;
    #pragma unroll
    for (int ks = 0; ks < 2; ks++)
      boff[n][ks] = 4096 + (col >> 6) * 2048 + swz(col & 63, 2 * ks + hi);
  }

  f32x16 acc[2][NFR];
  #pragma unroll
  for (int m = 0; m < 2; m++)
    #pragma unroll
    for (int n = 0; n < NFR; n++)
      #pragma unroll
      for (int e = 0; e < 16; e++) acc[m][n][e] = 0.f;

#define STAGE_A(c, tt, b2) \
  gld_lds16(A + (size_t)(mb + (c)*64 + sRow) * K + (size_t)(tt)*32 + sKc, \
            lds + (b2)*BUFH + (c)*2048 + tid*8)
#define STAGE_B(c, tt, b2) \
  gld_lds16(Bt + (size_t)(nb + (c)*64 + sRow) * K + (size_t)(tt)*32 + sKc, \
            lds + (b2)*BUFH + 4096 + (c)*2048 + tid*8)
#define WAIT_GLD() do { if constexpr (GLD == 6) asm volatile("s_waitcnt vmcnt(6)" ::: "memory"); \
                        else if constexpr (GLD == 4) asm volatile("s_waitcnt vmcnt(4)" ::: "memory"); \
                        else asm volatile("s_waitcnt vmcnt(3)" ::: "memory"); } while(0)

  // prologue: tile0 -> buf0, tile1 -> buf1
  STAGE_A(0, 0, 0); STAGE_A(1, 0, 0);
  #pragma unroll
  for (int c = 0; c < NFR; c++) STAGE_B(c, 0, 0);
  if (nk > 1){
    STAGE_A(0, 1, 1); STAGE_A(1, 1, 1);
    #pragma unroll
    for (int c = 0; c < NFR; c++) STAGE_B(c, 1, 1);
    WAIT_GLD();
  } else {
    asm volatile("s_waitcnt vmcnt(0)" ::: "memory");
  }
  asm volatile("" ::: "memory");
  __builtin_amdgcn_s_barrier();
  asm volatile("" ::: "memory");

  int bb = 0;
  for (int u = 0; u < nk; u++){
    const unsigned short* buf = lds + bb * BUFH;
    const int sb = (bb >= 1) ? bb - 1 : 2;      // (bb+2)%3
    const bool st = (u + 2 < nk);
    short8 af[2], bf[NFR];

    // ---- kstep 0 ----
    af[0] = *(const short8*)(buf + aoff[0][0]);
    af[1] = *(const short8*)(buf + aoff[1][0]);
    #pragma unroll
    for (int n = 0; n < NFR; n++) bf[n] = *(const short8*)(buf + boff[n][0]);
    if (st){
      STAGE_A(0, u + 2, sb); STAGE_A(1, u + 2, sb);
      if constexpr (NFR == 4) STAGE_B(0, u + 2, sb);
    }
    __builtin_amdgcn_s_setprio(1);
    #pragma unroll
    for (int m = 0; m < 2; m++)
      #pragma unroll
      for (int n = 0; n < NFR; n++)
        acc[m][n] = __builtin_amdgcn_mfma_f32_32x32x16_bf16(af[m], bf[n], acc[m][n], 0, 0, 0);
    __builtin_amdgcn_s_setprio(0);

    // ---- kstep 1 ----
    af[0] = *(const short8*)(buf + aoff[0][1]);
    af[1] = *(const short8*)(buf + aoff[1][1]);
    #pragma unroll
    for (int n = 0; n < NFR; n++) bf[n] = *(const short8*)(buf + boff[n][1]);
    if (st){
      if constexpr (NFR == 4){ STAGE_B(1, u + 2, sb); STAGE_B(2, u + 2, sb); STAGE_B(3, u + 2, sb); }
      else if constexpr (NFR == 2){ STAGE_B(0, u + 2, sb); STAGE_B(1, u + 2, sb); }
      else { STAGE_B(0, u + 2, sb); }
    }
    __builtin_amdgcn_s_setprio(1);
    #pragma unroll
    for (int m = 0; m < 2; m++)
      #pragma unroll
      for (int n = 0; n < NFR; n++)
        acc[m][n] = __builtin_amdgcn_mfma_f32_32x32x16_bf16(af[m], bf[n], acc[m][n], 0, 0, 0);
    __builtin_amdgcn_s_setprio(0);

    if (st)               WAIT_GLD();
    else if (u + 1 < nk)  asm volatile("s_waitcnt vmcnt(0)" ::: "memory");
    asm volatile("" ::: "memory");
    __builtin_amdgcn_s_barrier();
    asm volatile("" ::: "memory");
    bb = (bb == 2) ? 0 : bb + 1;
  }
#undef WAIT_GLD
#undef STAGE_A
#undef STAGE_B

  // epilogue: col = lane&31, row = (reg&3) + 8*(reg>>2) + 4*hi  [m74/m101]
  #pragma unroll
  for (int n = 0; n < NFR; n++){
    const int col = nb + wcn * (BN / 2) + n * 32 + r31;
    const float bv = bias ? bias[col] : 0.f;
    #pragma unroll
    for (int m = 0; m < 2; m++){
      const int rowb = mb + wr * 64 + m * 32 + 4 * hi;
      #pragma unroll
      for (int reg = 0; reg < 16; reg++){
        const int row = rowb + (reg & 3) + 8 * (reg >> 2);
        float v = acc[m][n][reg] + bv;
        size_t idx = (size_t)row * N + col;
        if (EPI == 0)       ((float*)C)[idx] = v;
        else if (EPI == 3)  __builtin_nontemporal_store(v, &((float*)C)[idx]);
        else if (EPI == 1)  ((unsigned short*)C)[idx] = f2bf(v);
        else { v = v > 0.f ? v : 0.f; ((unsigned short*)C)[idx] = f2bf(v); }
      }
    }
  }
}

// ---------------- Flash attention: 64 q-rows / block (4 waves x 16), dh=64, H=16 ----------------
template<int CAUSAL>
__global__ __launch_bounds__(256)
void attn_kernel(const unsigned short* __restrict__ Qb, int ldq,
                 const unsigned short* __restrict__ Kb, int ldk,
                 const unsigned short* __restrict__ Vb, int ldv,
                 unsigned short* __restrict__ Ob, int ldo)
{
  constexpr int S = 1024;
  __shared__ __align__(16) unsigned short vt[64][40];
  __shared__ __align__(16) unsigned short plds[4][16][40];
  const int tid = threadIdx.x, w = tid >> 6, l = tid & 63;
  const int qt = blockIdx.x, bh = blockIdx.y;
  const int b = bh >> 4, h = bh & 15;
  const int hoff = h * 64;
  const size_t rb = (size_t)b * S;

  const int qrow = qt * 64 + w * 16 + (l & 15);
  const unsigned short* qp = Qb + (rb + qrow) * ldq + hoff + ((l >> 4) * 8);
  short8 qf0 = *(const short8*)qp;
  short8 qf1 = *(const short8*)(qp + 32);

  float m_run[4] = {-1e30f, -1e30f, -1e30f, -1e30f};
  float l_run[4] = {0.f, 0.f, 0.f, 0.f};
  f32x4 oacc[4];
  #pragma unroll
  for (int t = 0; t < 4; t++) oacc[t] = (f32x4){0.f, 0.f, 0.f, 0.f};

  const int qmax = qt * 64 + w * 16 + 15;
  const int nkeys = CAUSAL ? (qt * 64 + 64) : S;
  const int skey = tid >> 3, sd8 = (tid & 7) * 8;

  for (int kb = 0; kb < nkeys; kb += 32){
    short8 vv = *(const short8*)(Vb + (rb + kb + skey) * ldv + hoff + sd8);
    #pragma unroll
    for (int i = 0; i < 8; i++) vt[sd8 + i][skey] = (unsigned short)vv[i];
    __syncthreads();
    if (!CAUSAL || kb <= qmax){
      f32x4 sc[2];
      #pragma unroll
      for (int g = 0; g < 2; g++){
        const unsigned short* kp = Kb + (rb + kb + g * 16 + (l & 15)) * ldk + hoff + ((l >> 4) * 8);
        short8 kf0 = *(const short8*)kp;
        short8 kf1 = *(const short8*)(kp + 32);
        f32x4 z = (f32x4){0.f, 0.f, 0.f, 0.f};
        z = __builtin_amdgcn_mfma_f32_16x16x32_bf16(qf0, kf0, z, 0, 0, 0);
        z = __builtin_amdgcn_mfma_f32_16x16x32_bf16(qf1, kf1, z, 0, 0, 0);
        sc[g] = z;
      }
      #pragma unroll
      for (int jj = 0; jj < 4; jj++){
        float s0 = sc[0][jj] * 0.125f, s1 = sc[1][jj] * 0.125f;
        if (CAUSAL){
          int q = qt * 64 + w * 16 + ((l >> 4) << 2) + jj;
          if (kb + (l & 15) > q)      s0 = -1e30f;
          if (kb + 16 + (l & 15) > q) s1 = -1e30f;
        }
        float mx = fmaxf(s0, s1);
        mx = fmaxf(mx, __shfl_xor(mx, 1));
        mx = fmaxf(mx, __shfl_xor(mx, 2));
        mx = fmaxf(mx, __shfl_xor(mx, 4));
        mx = fmaxf(mx, __shfl_xor(mx, 8));
        float mnew = fmaxf(m_run[jj], mx);
        float scal = __expf(m_run[jj] - mnew);
        m_run[jj] = mnew;
        float p0 = __expf(s0 - mnew), p1 = __expf(s1 - mnew);
        float rs = p0 + p1;
        rs += __shfl_xor(rs, 1); rs += __shfl_xor(rs, 2);
        rs += __shfl_xor(rs, 4); rs += __shfl_xor(rs, 8);
        l_run[jj] = l_run[jj] * scal + rs;
        #pragma unroll
        for (int t = 0; t < 4; t++) oacc[t][jj] *= scal;
        int qr = ((l >> 4) << 2) + jj;
        plds[w][qr][l & 15]      = f2bf(p0);
        plds[w][qr][16 + (l & 15)] = f2bf(p1);
      }
      asm volatile("s_waitcnt lgkmcnt(0)" ::: "memory");
      short8 pf = *(const short8*)&plds[w][l & 15][(l >> 4) * 8];
      #pragma unroll
      for (int t = 0; t < 4; t++){
        short8 vf = *(const short8*)&vt[t * 16 + (l & 15)][(l >> 4) * 8];
        oacc[t] = __builtin_amdgcn_mfma_f32_16x16x32_bf16(pf, vf, oacc[t], 0, 0, 0);
      }
    }
    __syncthreads();
  }
  #pragma unroll
  for (int jj = 0; jj < 4; jj++){
    float inv = 1.f / l_run[jj];
    int q = qt * 64 + w * 16 + ((l >> 4) << 2) + jj;
    #pragma unroll
    for (int t = 0; t < 4; t++)
      Ob[(rb + q) * ldo + hoff + t * 16 + (l & 15)] = f2bf(oacc[t][jj] * inv);
  }
}

// ---------------- LayerNorm over D=1024 ----------------
__global__ __launch_bounds__(256)
void ln_kernel(const float* __restrict__ x1, const float* __restrict__ x2,
               const float* __restrict__ g, const float* __restrict__ be,
               float* __restrict__ outf, unsigned short* __restrict__ outb)
{
  const int row = blockIdx.x, t = threadIdx.x;
  __shared__ float red[4];
  const float4 v1 = ((const float4*)(x1 + (size_t)row * 1024))[t];
  const float4 v2 = ((const float4*)(x2 + (size_t)row * 1024))[t];
  float x[4] = {v1.x + v2.x, v1.y + v2.y, v1.z + v2.z, v1.w + v2.w};
  float s = x[0] + x[1] + x[2] + x[3];
  for (int o = 1; o < 64; o <<= 1) s += __shfl_xor(s, o);
  const int w = t >> 6, l = t & 63;
  if (l == 0) red[w] = s;
  __syncthreads();
  const float mean = (red[0] + red[1] + red[2] + red[3]) * (1.f / 1024.f);
  float d[4]; float sq = 0.f;
  #pragma unroll
  for (int i = 0; i < 4; i++){ d[i] = x[i] - mean; sq += d[i] * d[i]; }
  __syncthreads();
  for (int o = 1; o < 64; o <<= 1) sq += __shfl_xor(sq, o);
  if (l == 0) red[w] = sq;
  __syncthreads();
  const float var = (red[0] + red[1] + red[2] + red[3]) * (1.f / 1024.f);
  const float inv = rsqrtf(var + 1e-5f);
  const int base = t * 4;
  #pragma unroll
  for (int i = 0; i < 4; i++){
    float o = d[i] * inv * g[base + i] + be[base + i];
    if (outf) outf[(size_t)row * 1024 + base + i] = o;
    outb[(size_t)row * 1024 + base + i] = f2bf(o);
  }
}

// ---------------- x0 = dec + positional encoding ----------------
__global__ __launch_bounds__(256)
void build_x0(const float* __restrict__ dec, float* __restrict__ xf, unsigned short* __restrict__ xb)
{
  const int i = blockIdx.x * 256 + threadIdx.x;
  const int i4 = i * 4;
  const int d0 = i4 & 1023;
  const int s  = (i4 >> 10) & 1023;
  float4 dv = ((const float4*)dec)[i];
  const float* dvp = (const float*)&dv;
  float o[4];
  #pragma unroll
  for (int j = 0; j < 4; j++){
    int dd = d0 + j;
    float e = (float)(dd & ~1) * (1.f / 1024.f);
    float den = expf(e * 9.210340371976184f);
    float ang = (float)s / den;
    float pe = (dd & 1) ? cosf(ang) : sinf(ang);
    o[j] = dvp[j] + pe;
  }
  ((float4*)xf)[i] = make_float4(o[0], o[1], o[2], o[3]);
  ushort4v ob; ob[0] = f2bf(o[0]); ob[1] = f2bf(o[1]); ob[2] = f2bf(o[2]); ob[3] = f2bf(o[3]);
  ((ushort4v*)xb)[i] = ob;
}

__global__ __launch_bounds__(256)
void cvt_bf16_k(const float* __restrict__ in, unsigned short* __restrict__ out)
{
  const int i = blockIdx.x * 256 + threadIdx.x;
  float4 v = ((const float4*)in)[i];
  ushort4v o; o[0] = f2bf(v.x); o[1] = f2bf(v.y); o[2] = f2bf(v.z); o[3] = f2bf(v.w);
  ((ushort4v*)out)[i] = o;
}

// ---------------- transpose + convert: in[R][C] f32 -> out[C][R] bf16 ----------------
// 64R x 32C tiles; writes are 128B-coalesced rows of 64 bf16.
__global__ __launch_bounds__(256)
void transpose_cvt(const float* __restrict__ in, unsigned short* __restrict__ out, int R, int C)
{
  __shared__ float t[32][65];
  const int cb = blockIdx.x * 32, rb = blockIdx.y * 64;
  const int tx = threadIdx.x & 31, ty = threadIdx.x >> 5;   // 32 x 8
  #pragma unroll
  for (int i = 0; i < 8; i++)
    t[tx][ty + 8 * i] = in[(size_t)(rb + ty + 8 * i) * C + cb + tx];
  __syncthreads();
  const int lane = threadIdx.x & 63, cr = threadIdx.x >> 6; // 64 x 4
  #pragma unroll
  for (int j = 0; j < 8; j++){
    int c = cr + 4 * j;
    out[(size_t)(cb + c) * R + rb + lane] = f2bf(t[c][lane]);
  }
}

struct TPtrs { const float* src[8]; unsigned short* dst[8]; };
__global__ __launch_bounds__(256)
void transpose_cvt8(TPtrs p)
{
  __shared__ float t[32][65];
  const float* __restrict__ in = p.src[blockIdx.z];
  unsigned short* __restrict__ out = p.dst[blockIdx.z];
  const int cb = blockIdx.x * 32, rb = blockIdx.y * 64;
  const int tx = threadIdx.x & 31, ty = threadIdx.x >> 5;
  #pragma unroll
  for (int i = 0; i < 8; i++)
    t[tx][ty + 8 * i] = in[(size_t)(rb + ty + 8 * i) * 1024 + cb + tx];
  __syncthreads();
  const int lane = threadIdx.x & 63, cr = threadIdx.x >> 6;
  #pragma unroll
  for (int j = 0; j < 8; j++){
    int c = cr + 4 * j;
    out[(size_t)(cb + c) * 1024 + rb + lane] = f2bf(t[c][lane]);
  }
}

__global__ __launch_bounds__(256)
void copy_biases(const float* sbq, const float* sbk, const float* sbv,
                 const float* cbk, const float* cbv,
                 float* bqkv, float* bkvc)
{
  const int i = blockIdx.x * 256 + threadIdx.x;
  const int seg = i >> 10, off = i & 1023;
  if (seg == 0)      bqkv[off] = sbq[off];
  else if (seg == 1) bqkv[1024 + off] = sbk[off];
  else if (seg == 2) bqkv[2048 + off] = sbv[off];
  else if (seg == 3) bkvc[off] = cbk[off];
  else               bkvc[1024 + off] = cbv[off];
}

extern "C" void kernel_launch(void* const* d_in, const int* in_sizes, int n_in,
                              void* d_out, int out_size, void* d_ws, size_t ws_size,
                              hipStream_t stream)
{
  constexpr int S = 1024, D = 1024, V = 32000, DF = 4096;
  constexpr int M = 2 * S;
  constexpr int DD = D * D;
  constexpr int l3 = 3;

  const float* dec  = (const float*)d_in[0];
  const float* enc  = (const float*)d_in[1];
  const float* sWq = (const float*)d_in[5]  + l3 * DD;
  const float* sWk = (const float*)d_in[6]  + l3 * DD;
  const float* sWv = (const float*)d_in[7]  + l3 * DD;
  const float* sWo = (const float*)d_in[8]  + l3 * DD;
  const float* cWq = (const float*)d_in[9]  + l3 * DD;
  const float* cWk = (const float*)d_in[10] + l3 * DD;
  const float* cWv = (const float*)d_in[11] + l3 * DD;
  const float* cWo = (const float*)d_in[12] + l3 * DD;
  const float* sbq = (const float*)d_in[13] + l3 * D;
  const float* sbk = (const float*)d_in[14] + l3 * D;
  const float* sbv = (const float*)d_in[15] + l3 * D;
  const float* sbo = (const float*)d_in[16] + l3 * D;
  const float* cbq = (const float*)d_in[17] + l3 * D;
  const float* cbk = (const float*)d_in[18] + l3 * D;
  const float* cbv = (const float*)d_in[19] + l3 * D;
  const float* cbo = (const float*)d_in[20] + l3 * D;
  const float* ln1g = (const float*)d_in[21] + l3 * D;
  const float* ln2g = (const float*)d_in[22] + l3 * D;
  const float* ln3g = (const float*)d_in[23] + l3 * D;
  const float* ln1b = (const float*)d_in[24] + l3 * D;
  const float* ln2b = (const float*)d_in[25] + l3 * D;
  const float* ln3b = (const float*)d_in[26] + l3 * D;
  const float* fW1 = (const float*)d_in[27] + (size_t)l3 * D * DF;
  const float* fb1 = (const float*)d_in[28] + l3 * DF;
  const float* fW2 = (const float*)d_in[29] + (size_t)l3 * DF * D;
  const float* fb2 = (const float*)d_in[30] + l3 * D;
  const float* Wout = (const float*)d_in[31];
  const float* bout = (const float*)d_in[32];
  float* out = (float*)d_out;

  uint8_t* wsp = (uint8_t*)d_ws;
  auto alloc = [&](size_t bytes) -> void* {
    void* p = wsp; wsp += (bytes + 255) & ~(size_t)255; return p;
  };
  float*          x0f  = (float*)alloc((size_t)M * D * 4);
  unsigned short* x0b  = (unsigned short*)alloc((size_t)M * D * 2);
  unsigned short* encb = (unsigned short*)alloc((size_t)M * D * 2);
  unsigned short* wqkv = (unsigned short*)alloc((size_t)3 * DD * 2);
  unsigned short* wos  = (unsigned short*)alloc((size_t)DD * 2);
  unsigned short* wqc  = (unsigned short*)alloc((size_t)DD * 2);
  unsigned short* wkvc = (unsigned short*)alloc((size_t)2 * DD * 2);
  unsigned short* woc  = (unsigned short*)alloc((size_t)DD * 2);
  unsigned short* wf1  = (unsigned short*)alloc((size_t)D * DF * 2);
  unsigned short* wf2  = (unsigned short*)alloc((size_t)D * DF * 2);
  unsigned short* wvo  = (unsigned short*)alloc((size_t)V * D * 2);
  float*          bqkv = (float*)alloc(3 * D * 4);
  float*          bkvc = (float*)alloc(2 * D * 4);
  unsigned short* qkv  = (unsigned short*)alloc((size_t)M * 3 * D * 2);
  unsigned short* attnb= (unsigned short*)alloc((size_t)M * D * 2);
  float*          oproj= (float*)alloc((size_t)M * D * 4);
  float*          a1f  = (float*)alloc((size_t)M * D * 4);
  unsigned short* a1b  = (unsigned short*)alloc((size_t)M * D * 2);
  unsigned short* qc   = (unsigned short*)alloc((size_t)M * D * 2);
  unsigned short* kvc  = (unsigned short*)alloc((size_t)M * 2 * D * 2);
  float*          a2f  = (float*)alloc((size_t)M * D * 4);
  unsigned short* a2b  = (unsigned short*)alloc((size_t)M * D * 2);
  unsigned short* ffh  = (unsigned short*)alloc((size_t)M * DF * 2);
  unsigned short* yb   = (unsigned short*)alloc((size_t)M * D * 2);

  build_x0<<<M * D / 4 / 256, 256, 0, stream>>>(dec, x0f, x0b);
  cvt_bf16_k<<<M * D / 4 / 256, 256, 0, stream>>>(enc, encb);

  TPtrs tp;
  tp.src[0] = sWq; tp.dst[0] = wqkv;
  tp.src[1] = sWk; tp.dst[1] = wqkv + DD;
  tp.src[2] = sWv; tp.dst[2] = wqkv + 2 * DD;
  tp.src[3] = sWo; tp.dst[3] = wos;
  tp.src[4] = cWq; tp.dst[4] = wqc;
  tp.src[5] = cWk; tp.dst[5] = wkvc;
  tp.src[6] = cWv; tp.dst[6] = wkvc + DD;
  tp.src[7] = cWo; tp.dst[7] = woc;
  transpose_cvt8<<<dim3(32, 16, 8), 256, 0, stream>>>(tp);
  transpose_cvt<<<dim3(DF/32, D/64), 256, 0, stream>>>(fW1, wf1, D, DF);
  transpose_cvt<<<dim3(D/32, DF/64), 256, 0, stream>>>(fW2, wf2, DF, D);
  transpose_cvt<<<dim3(V/32, D/64), 256, 0, stream>>>(Wout, wvo, D, V);
  copy_biases<<<20, 256, 0, stream>>>(sbq, sbk, sbv, cbk, cbv, bqkv, bkvc);

  // 3. self-attention block
  gemm32<128,1><<<(M/128)*(3*D/128), 256, 0, stream>>>(x0b, wqkv, bqkv, qkv, M, 3*D, D);
  attn_kernel<1><<<dim3(S/64, 32), 256, 0, stream>>>(qkv, 3*D, qkv + D, 3*D, qkv + 2*D, 3*D, attnb, D);
  gemm32<64,0><<<(M/128)*(D/64), 256, 0, stream>>>(attnb, wos, sbo, oproj, M, D, D);
  ln_kernel<<<M, 256, 0, stream>>>(x0f, oproj, ln1g, ln1b, a1f, a1b);

  // 4. cross-attention block
  gemm32<64,1><<<(M/128)*(D/64), 256, 0, stream>>>(a1b, wqc, cbq, qc, M, D, D);
  gemm32<128,1><<<(M/128)*(2*D/128), 256, 0, stream>>>(encb, wkvc, bkvc, kvc, M, 2*D, D);
  attn_kernel<0><<<dim3(S/64, 32), 256, 0, stream>>>(qc, D, kvc, 2*D, kvc + D, 2*D, attnb, D);
  gemm32<64,0><<<(M/128)*(D/64), 256, 0, stream>>>(attnb, woc, cbo, oproj, M, D, D);
  ln_kernel<<<M, 256, 0, stream>>>(a1f, oproj, ln2g, ln2b, a2f, a2b);

  // 5. FFN
  gemm32<256,2><<<(M/128)*(DF/256), 256, 0, stream>>>(a2b, wf1, fb1, ffh, M, DF, D);
  gemm32<64,0><<<(M/128)*(D/64), 256, 0, stream>>>(ffh, wf2, fb2, oproj, M, D, DF);
  ln_kernel<<<M, 256, 0, stream>>>(a2f, oproj, ln3g, ln3b, nullptr, yb);

  // 6. logits
  gemm32<256,3><<<(M/128)*(V/256), 256, 0, stream>>>(yb, wvo, bout, out, M, V, D);
}

// Round 8
// 524.882 us; speedup vs baseline: 1.2335x; 1.1500x over previous
//
#include <hip/hip_runtime.h>
#include <cstdint>
#include <cstddef>

#define DEV __device__ __forceinline__

typedef __attribute__((ext_vector_type(8))) short short8;
typedef __attribute__((ext_vector_type(4))) float f32x4;
typedef __attribute__((ext_vector_type(16))) float f32x16;
typedef __attribute__((ext_vector_type(4))) unsigned short ushort4v;

DEV unsigned short f2bf(float f){
  union { float f; unsigned int i; } v; v.f = f;
  unsigned int r = v.i + 0x7fffu + ((v.i >> 16) & 1u);
  return (unsigned short)(r >> 16);
}

DEV void gld_lds16(const unsigned short* g, unsigned short* lds){
  __builtin_amdgcn_global_load_lds((const __attribute__((address_space(1))) void*)g,
                                   (__attribute__((address_space(3))) void*)lds, 16, 0, 0);
}

// swizzled offset (halves) of (row r, k-slot s) within a 64-row chunk (GEMM layout).
DEV int swz(int r, int s){
  int ln = r >> 1;
  int sl = ((r & 1) << 2) | s;
  return ln * 64 + (((sl ^ (ln & 7))) << 3);
}

// =================== 128xBN 4-wave GEMM on 32x32x16 MFMA, 3-buffer pipeline ===================
template<int BN, int EPI>
__global__ __launch_bounds__(256, 2)
void gemm32(const unsigned short* __restrict__ A,
            const unsigned short* __restrict__ Bt,
            const float* __restrict__ bias,
            void* __restrict__ C, int M, int N, int K)
{
  constexpr int NFR  = BN / 64;
  constexpr int ROWS = 128 + BN;
  constexpr int BUFH = ROWS * 32;
  constexpr int GLD  = ROWS / 64;
  __shared__ __align__(16) unsigned short lds[3 * BUFH];

  const int tid = threadIdx.x, wid = tid >> 6, l = tid & 63;
  const int wr = wid >> 1, wcn = wid & 1;

  const int nbm = M / 128, nbn = N / BN;
  const int nwg = nbm * nbn;
  const int q8 = nwg >> 3, r8 = nwg & 7;
  const int xcd = blockIdx.x & 7, within = blockIdx.x >> 3;
  const int wg = (xcd < r8 ? xcd * (q8 + 1) : r8 * (q8 + 1) + (xcd - r8) * q8) + within;
  const int mb = (wg % nbm) * 128, nb = (wg / nbm) * BN;

  const int nk = K / 32;

  const int sL   = tid >> 3;
  const int sSl  = (tid & 7) ^ (sL & 7);
  const int sRow = sL * 2 + (sSl >> 2);
  const int sKc  = (sSl & 3) * 8;

  const int r31 = l & 31, hi = l >> 5;

  int aoff[2][2], boff[NFR][2];
  #pragma unroll
  for (int m = 0; m < 2; m++)
    #pragma unroll
    for (int ks = 0; ks < 2; ks++)
      aoff[m][ks] = wr * 2048 + swz(m * 32 + r31, 2 * ks + hi);
  #pragma unroll
  for (int n = 0; n < NFR; n++){
    const int col = wcn * (BN / 2) + n * 32 + r31;
    #pragma unroll
    for (int ks = 0; ks < 2; ks++)
      boff[n][ks] = 4096 + (col >> 6) * 2048 + swz(col & 63, 2 * ks + hi);
  }

  f32x16 acc[2][NFR];
  #pragma unroll
  for (int m = 0; m < 2; m++)
    #pragma unroll
    for (int n = 0; n < NFR; n++)
      #pragma unroll
      for (int e = 0; e < 16; e++) acc[m][n][e] = 0.f;

#define STAGE_A(c, tt, b2) \
  gld_lds16(A + (size_t)(mb + (c)*64 + sRow) * K + (size_t)(tt)*32 + sKc, \
            lds + (b2)*BUFH + (c)*2048 + tid*8)
#define STAGE_B(c, tt, b2) \
  gld_lds16(Bt + (size_t)(nb + (c)*64 + sRow) * K + (size_t)(tt)*32 + sKc, \
            lds + (b2)*BUFH + 4096 + (c)*2048 + tid*8)
#define WAIT_GLD() do { if constexpr (GLD == 6) asm volatile("s_waitcnt vmcnt(6)" ::: "memory"); \
                        else if constexpr (GLD == 4) asm volatile("s_waitcnt vmcnt(4)" ::: "memory"); \
                        else asm volatile("s_waitcnt vmcnt(3)" ::: "memory"); } while(0)

  STAGE_A(0, 0, 0); STAGE_A(1, 0, 0);
  #pragma unroll
  for (int c = 0; c < NFR; c++) STAGE_B(c, 0, 0);
  if (nk > 1){
    STAGE_A(0, 1, 1); STAGE_A(1, 1, 1);
    #pragma unroll
    for (int c = 0; c < NFR; c++) STAGE_B(c, 1, 1);
    WAIT_GLD();
  } else {
    asm volatile("s_waitcnt vmcnt(0)" ::: "memory");
  }
  asm volatile("" ::: "memory");
  __builtin_amdgcn_s_barrier();
  asm volatile("" ::: "memory");

  int bb = 0;
  for (int u = 0; u < nk; u++){
    const unsigned short* buf = lds + bb * BUFH;
    const int sb = (bb >= 1) ? bb - 1 : 2;
    const bool st = (u + 2 < nk);
    short8 af[2], bf[NFR];

    af[0] = *(const short8*)(buf + aoff[0][0]);
    af[1] = *(const short8*)(buf + aoff[1][0]);
    #pragma unroll
    for (int n = 0; n < NFR; n++) bf[n] = *(const short8*)(buf + boff[n][0]);
    if (st){
      STAGE_A(0, u + 2, sb); STAGE_A(1, u + 2, sb);
      if constexpr (NFR == 4) STAGE_B(0, u + 2, sb);
    }
    __builtin_amdgcn_s_setprio(1);
    #pragma unroll
    for (int m = 0; m < 2; m++)
      #pragma unroll
      for (int n = 0; n < NFR; n++)
        acc[m][n] = __builtin_amdgcn_mfma_f32_32x32x16_bf16(af[m], bf[n], acc[m][n], 0, 0, 0);
    __builtin_amdgcn_s_setprio(0);

    af[0] = *(const short8*)(buf + aoff[0][1]);
    af[1] = *(const short8*)(buf + aoff[1][1]);
    #pragma unroll
    for (int n = 0; n < NFR; n++) bf[n] = *(const short8*)(buf + boff[n][1]);
    if (st){
      if constexpr (NFR == 4){ STAGE_B(1, u + 2, sb); STAGE_B(2, u + 2, sb); STAGE_B(3, u + 2, sb); }
      else if constexpr (NFR == 2){ STAGE_B(0, u + 2, sb); STAGE_B(1, u + 2, sb); }
      else { STAGE_B(0, u + 2, sb); }
    }
    __builtin_amdgcn_s_setprio(1);
    #pragma unroll
    for (int m = 0; m < 2; m++)
      #pragma unroll
      for (int n = 0; n < NFR; n++)
        acc[m][n] = __builtin_amdgcn_mfma_f32_32x32x16_bf16(af[m], bf[n], acc[m][n], 0, 0, 0);
    __builtin_amdgcn_s_setprio(0);

    if (st)               WAIT_GLD();
    else if (u + 1 < nk)  asm volatile("s_waitcnt vmcnt(0)" ::: "memory");
    asm volatile("" ::: "memory");
    __builtin_amdgcn_s_barrier();
    asm volatile("" ::: "memory");
    bb = (bb == 2) ? 0 : bb + 1;
  }
#undef WAIT_GLD
#undef STAGE_A
#undef STAGE_B

  #pragma unroll
  for (int n = 0; n < NFR; n++){
    const int col = nb + wcn * (BN / 2) + n * 32 + r31;
    const float bv = bias ? bias[col] : 0.f;
    #pragma unroll
    for (int m = 0; m < 2; m++){
      const int rowb = mb + wr * 64 + m * 32 + 4 * hi;
      #pragma unroll
      for (int reg = 0; reg < 16; reg++){
        const int row = rowb + (reg & 3) + 8 * (reg >> 2);
        float v = acc[m][n][reg] + bv;
        size_t idx = (size_t)row * N + col;
        if (EPI == 0)       ((float*)C)[idx] = v;
        else if (EPI == 3)  __builtin_nontemporal_store(v, &((float*)C)[idx]);
        else if (EPI == 1)  ((unsigned short*)C)[idx] = f2bf(v);
        else { v = v > 0.f ? v : 0.f; ((unsigned short*)C)[idx] = f2bf(v); }
      }
    }
  }
}

// ======= Flash attention v2: 64 q-rows/block, KVBLK=64, LDS-staged K + V^T, dbuf =======
// K: [2][64 rows][64 halves] linear, slot-XOR phys = slot ^ (row&7), staged via
// pre-swizzled global source (rule #21). Reads (row = 16g+(l&15), slot h*4+(l>>4))
// land 2 lanes/slot = free. V^T: [2][64 d][64 halves], scalar transpose writes with
// phys = (k>>3) ^ (d&7) ^ ((d>>3)&7) -- write instr spreads 8 slots over l&7 (was
// 8-way conflicted in v1); reads 2-way. One __syncthreads per 64-key tile; async
// K-stage + V-load issued before compute (T14), V^T write after vmcnt(0) at tail.
// Causal: mask only the diagonal tile (u == qt); earlier tiles fully visible.
template<int CAUSAL>
__global__ __launch_bounds__(256)
void attn_kernel(const unsigned short* __restrict__ Qb, int ldq,
                 const unsigned short* __restrict__ Kb, int ldk,
                 const unsigned short* __restrict__ Vb, int ldv,
                 unsigned short* __restrict__ Ob, int ldo)
{
  constexpr int S = 1024;
  __shared__ __align__(16) unsigned short klds[2][4096];
  __shared__ __align__(16) unsigned short vlds[2][4096];
  __shared__ __align__(16) unsigned short plds[4][16][72];

  const int tid = threadIdx.x, w = tid >> 6, l = tid & 63;
  const int qt = blockIdx.x, bh = blockIdx.y;
  const int b = bh >> 4, h = bh & 15;
  const int hoff = h * 64;
  const size_t rb = (size_t)b * S;

  const int qrow = qt * 64 + w * 16 + (l & 15);
  const unsigned short* qp = Qb + (rb + qrow) * ldq + hoff + ((l >> 4) * 8);
  short8 qf0 = *(const short8*)qp;
  short8 qf1 = *(const short8*)(qp + 32);

  float m_run[4] = {-1e30f, -1e30f, -1e30f, -1e30f};
  float l_run[4] = {0.f, 0.f, 0.f, 0.f};
  f32x4 oacc[4];
  #pragma unroll
  for (int t = 0; t < 4; t++) oacc[t] = (f32x4){0.f, 0.f, 0.f, 0.f};

  const int nkv = CAUSAL ? (qt + 1) : (S / 64);

  // staging constants
  const int sRowK  = tid >> 3;                         // 0..31 (chunk-local row)
  const int sSlotK = (tid & 7) ^ ((tid >> 3) & 7);     // pre-swizzled source slot
  const int skey   = tid >> 3;                         // V source row (pass adds 32)
  const int sd8    = (tid & 7) * 8;                    // V source d-offset

  // K read offsets: row 16g+(l&15), slot h*4+(l>>4), phys = slot ^ (row&7)
  int koff[4][2];
  #pragma unroll
  for (int g = 0; g < 4; g++)
    #pragma unroll
    for (int hh = 0; hh < 2; hh++)
      koff[g][hh] = (16 * g + (l & 15)) * 64 + (((hh * 4 + (l >> 4)) ^ (l & 7)) << 3);

  // V^T read offsets: row d = 16t+(l&15), slot ks*4+(l>>4),
  // phys = slot ^ (d&7) ^ ((d>>3)&7);  (d>>3)&7 = 2t + ((l>>3)&1)
  const int vpar = (l >> 3) & 1;
  int voff[4][2];
  #pragma unroll
  for (int t = 0; t < 4; t++)
    #pragma unroll
    for (int ks = 0; ks < 2; ks++)
      voff[t][ks] = (16 * t + (l & 15)) * 64 +
                    ((((ks * 4 + (l >> 4)) ^ (l & 7) ^ ((2 * t + vpar) & 7))) << 3);

#define STAGE_K(c, kt, bf) \
  gld_lds16(Kb + (rb + (size_t)(kt) * 64 + (c) * 32 + sRowK) * ldk + hoff + sSlotK * 8, \
            &klds[bf][(c) * 2048 + tid * 8])
#define LOAD_V(kt, r0v, r1v) do { \
  r0v = *(const short8*)(Vb + (rb + (size_t)(kt) * 64 + skey) * ldv + hoff + sd8); \
  r1v = *(const short8*)(Vb + (rb + (size_t)(kt) * 64 + 32 + skey) * ldv + hoff + sd8); } while(0)
// write elem (d = sd8+i, k = skey+32p): phys = (w+4p)^i^(l&7); within-slot = l>>3
#define WRITE_VT(bf, p, vv) do { \
  _Pragma("unroll") \
  for (int i = 0; i < 8; i++){ \
    vlds[bf][(sd8 + i) * 64 + (((w + 4 * (p)) ^ i ^ (l & 7)) << 3) + (l >> 3)] = \
      (unsigned short)(vv)[i]; \
  } } while(0)

  short8 v0, v1;
  STAGE_K(0, 0, 0); STAGE_K(1, 0, 0);
  LOAD_V(0, v0, v1);
  asm volatile("s_waitcnt vmcnt(0)" ::: "memory");
  WRITE_VT(0, 0, v0); WRITE_VT(0, 1, v1);
  __syncthreads();

  for (int u = 0; u < nkv; u++){
    const int cur = u & 1, nxt = cur ^ 1;
    const bool pre = (u + 1 < nkv);
    if (pre){ STAGE_K(0, u + 1, nxt); STAGE_K(1, u + 1, nxt); LOAD_V(u + 1, v0, v1); }

    // ---- QK^T (64 keys) ----
    f32x4 sc[4];
    #pragma unroll
    for (int g = 0; g < 4; g++){
      short8 k0 = *(const short8*)&klds[cur][koff[g][0]];
      short8 k1 = *(const short8*)&klds[cur][koff[g][1]];
      f32x4 z = (f32x4){0.f, 0.f, 0.f, 0.f};
      z = __builtin_amdgcn_mfma_f32_16x16x32_bf16(qf0, k0, z, 0, 0, 0);
      z = __builtin_amdgcn_mfma_f32_16x16x32_bf16(qf1, k1, z, 0, 0, 0);
      sc[g] = z;
    }

    // ---- online softmax ----
    const bool diag = CAUSAL && (u == qt);
    const int kb = u * 64;
    #pragma unroll
    for (int jj = 0; jj < 4; jj++){
      float s0 = sc[0][jj] * 0.125f, s1 = sc[1][jj] * 0.125f;
      float s2 = sc[2][jj] * 0.125f, s3 = sc[3][jj] * 0.125f;
      if (diag){
        const int q = qt * 64 + w * 16 + ((l >> 4) << 2) + jj;
        const int ky = kb + (l & 15);
        if (ky      > q) s0 = -1e30f;
        if (ky + 16 > q) s1 = -1e30f;
        if (ky + 32 > q) s2 = -1e30f;
        if (ky + 48 > q) s3 = -1e30f;
      }
      float mx = fmaxf(fmaxf(s0, s1), fmaxf(s2, s3));
      mx = fmaxf(mx, __shfl_xor(mx, 1));
      mx = fmaxf(mx, __shfl_xor(mx, 2));
      mx = fmaxf(mx, __shfl_xor(mx, 4));
      mx = fmaxf(mx, __shfl_xor(mx, 8));
      float mnew = fmaxf(m_run[jj], mx);
      float scal = __expf(m_run[jj] - mnew);
      m_run[jj] = mnew;
      float p0 = __expf(s0 - mnew), p1 = __expf(s1 - mnew);
      float p2 = __expf(s2 - mnew), p3 = __expf(s3 - mnew);
      float rs = (p0 + p1) + (p2 + p3);
      rs += __shfl_xor(rs, 1); rs += __shfl_xor(rs, 2);
      rs += __shfl_xor(rs, 4); rs += __shfl_xor(rs, 8);
      l_run[jj] = l_run[jj] * scal + rs;
      #pragma unroll
      for (int t = 0; t < 4; t++) oacc[t][jj] *= scal;
      const int qr = ((l >> 4) << 2) + jj;
      plds[w][qr][l & 15]        = f2bf(p0);
      plds[w][qr][16 + (l & 15)] = f2bf(p1);
      plds[w][qr][32 + (l & 15)] = f2bf(p2);
      plds[w][qr][48 + (l & 15)] = f2bf(p3);
    }
    asm volatile("s_waitcnt lgkmcnt(0)" ::: "memory");
    __builtin_amdgcn_sched_barrier(0);

    // ---- PV ----
    short8 pf0 = *(const short8*)&plds[w][l & 15][(l >> 4) * 8];
    short8 pf1 = *(const short8*)&plds[w][l & 15][32 + (l >> 4) * 8];
    #pragma unroll
    for (int t = 0; t < 4; t++){
      short8 va = *(const short8*)&vlds[cur][voff[t][0]];
      short8 vb2 = *(const short8*)&vlds[cur][voff[t][1]];
      f32x4 o = oacc[t];
      o = __builtin_amdgcn_mfma_f32_16x16x32_bf16(pf0, va,  o, 0, 0, 0);
      o = __builtin_amdgcn_mfma_f32_16x16x32_bf16(pf1, vb2, o, 0, 0, 0);
      oacc[t] = o;
    }

    if (pre){
      asm volatile("s_waitcnt vmcnt(0)" ::: "memory");
      WRITE_VT(nxt, 0, v0); WRITE_VT(nxt, 1, v1);
    }
    __syncthreads();
  }
#undef WRITE_VT
#undef LOAD_V
#undef STAGE_K

  #pragma unroll
  for (int jj = 0; jj < 4; jj++){
    float inv = 1.f / l_run[jj];
    int q = qt * 64 + w * 16 + ((l >> 4) << 2) + jj;
    #pragma unroll
    for (int t = 0; t < 4; t++)
      Ob[(rb + q) * ldo + hoff + t * 16 + (l & 15)] = f2bf(oacc[t][jj] * inv);
  }
}

// ---------------- LayerNorm over D=1024 ----------------
__global__ __launch_bounds__(256)
void ln_kernel(const float* __restrict__ x1, const float* __restrict__ x2,
               const float* __restrict__ g, const float* __restrict__ be,
               float* __restrict__ outf, unsigned short* __restrict__ outb)
{
  const int row = blockIdx.x, t = threadIdx.x;
  __shared__ float red[4];
  const float4 v1 = ((const float4*)(x1 + (size_t)row * 1024))[t];
  const float4 v2 = ((const float4*)(x2 + (size_t)row * 1024))[t];
  float x[4] = {v1.x + v2.x, v1.y + v2.y, v1.z + v2.z, v1.w + v2.w};
  float s = x[0] + x[1] + x[2] + x[3];
  for (int o = 1; o < 64; o <<= 1) s += __shfl_xor(s, o);
  const int w = t >> 6, l = t & 63;
  if (l == 0) red[w] = s;
  __syncthreads();
  const float mean = (red[0] + red[1] + red[2] + red[3]) * (1.f / 1024.f);
  float d[4]; float sq = 0.f;
  #pragma unroll
  for (int i = 0; i < 4; i++){ d[i] = x[i] - mean; sq += d[i] * d[i]; }
  __syncthreads();
  for (int o = 1; o < 64; o <<= 1) sq += __shfl_xor(sq, o);
  if (l == 0) red[w] = sq;
  __syncthreads();
  const float var = (red[0] + red[1] + red[2] + red[3]) * (1.f / 1024.f);
  const float inv = rsqrtf(var + 1e-5f);
  const int base = t * 4;
  #pragma unroll
  for (int i = 0; i < 4; i++){
    float o = d[i] * inv * g[base + i] + be[base + i];
    if (outf) outf[(size_t)row * 1024 + base + i] = o;
    outb[(size_t)row * 1024 + base + i] = f2bf(o);
  }
}

// ---------------- x0 = dec + positional encoding ----------------
__global__ __launch_bounds__(256)
void build_x0(const float* __restrict__ dec, float* __restrict__ xf, unsigned short* __restrict__ xb)
{
  const int i = blockIdx.x * 256 + threadIdx.x;
  const int i4 = i * 4;
  const int d0 = i4 & 1023;
  const int s  = (i4 >> 10) & 1023;
  float4 dv = ((const float4*)dec)[i];
  const float* dvp = (const float*)&dv;
  float o[4];
  #pragma unroll
  for (int j = 0; j < 4; j++){
    int dd = d0 + j;
    float e = (float)(dd & ~1) * (1.f / 1024.f);
    float den = expf(e * 9.210340371976184f);
    float ang = (float)s / den;
    float pe = (dd & 1) ? cosf(ang) : sinf(ang);
    o[j] = dvp[j] + pe;
  }
  ((float4*)xf)[i] = make_float4(o[0], o[1], o[2], o[3]);
  ushort4v ob; ob[0] = f2bf(o[0]); ob[1] = f2bf(o[1]); ob[2] = f2bf(o[2]); ob[3] = f2bf(o[3]);
  ((ushort4v*)xb)[i] = ob;
}

__global__ __launch_bounds__(256)
void cvt_bf16_k(const float* __restrict__ in, unsigned short* __restrict__ out)
{
  const int i = blockIdx.x * 256 + threadIdx.x;
  float4 v = ((const float4*)in)[i];
  ushort4v o; o[0] = f2bf(v.x); o[1] = f2bf(v.y); o[2] = f2bf(v.z); o[3] = f2bf(v.w);
  ((ushort4v*)out)[i] = o;
}

// ---------------- transpose + convert: in[R][C] f32 -> out[C][R] bf16 ----------------
__global__ __launch_bounds__(256)
void transpose_cvt(const float* __restrict__ in, unsigned short* __restrict__ out, int R, int C)
{
  __shared__ float t[32][65];
  const int cb = blockIdx.x * 32, rb = blockIdx.y * 64;
  const int tx = threadIdx.x & 31, ty = threadIdx.x >> 5;
  #pragma unroll
  for (int i = 0; i < 8; i++)
    t[tx][ty + 8 * i] = in[(size_t)(rb + ty + 8 * i) * C + cb + tx];
  __syncthreads();
  const int lane = threadIdx.x & 63, cr = threadIdx.x >> 6;
  #pragma unroll
  for (int j = 0; j < 8; j++){
    int c = cr + 4 * j;
    out[(size_t)(cb + c) * R + rb + lane] = f2bf(t[c][lane]);
  }
}

struct TPtrs { const float* src[8]; unsigned short* dst[8]; };
__global__ __launch_bounds__(256)
void transpose_cvt8(TPtrs p)
{
  __shared__ float t[32][65];
  const float* __restrict__ in = p.src[blockIdx.z];
  unsigned short* __restrict__ out = p.dst[blockIdx.z];
  const int cb = blockIdx.x * 32, rb = blockIdx.y * 64;
  const int tx = threadIdx.x & 31, ty = threadIdx.x >> 5;
  #pragma unroll
  for (int i = 0; i < 8; i++)
    t[tx][ty + 8 * i] = in[(size_t)(rb + ty + 8 * i) * 1024 + cb + tx];
  __syncthreads();
  const int lane = threadIdx.x & 63, cr = threadIdx.x >> 6;
  #pragma unroll
  for (int j = 0; j < 8; j++){
    int c = cr + 4 * j;
    out[(size_t)(cb + c) * 1024 + rb + lane] = f2bf(t[c][lane]);
  }
}

__global__ __launch_bounds__(256)
void copy_biases(const float* sbq, const float* sbk, const float* sbv,
                 const float* cbk, const float* cbv,
                 float* bqkv, float* bkvc)
{
  const int i = blockIdx.x * 256 + threadIdx.x;
  const int seg = i >> 10, off = i & 1023;
  if (seg == 0)      bqkv[off] = sbq[off];
  else if (seg == 1) bqkv[1024 + off] = sbk[off];
  else if (seg == 2) bqkv[2048 + off] = sbv[off];
  else if (seg == 3) bkvc[off] = cbk[off];
  else               bkvc[1024 + off] = cbv[off];
}

extern "C" void kernel_launch(void* const* d_in, const int* in_sizes, int n_in,
                              void* d_out, int out_size, void* d_ws, size_t ws_size,
                              hipStream_t stream)
{
  constexpr int S = 1024, D = 1024, V = 32000, DF = 4096;
  constexpr int M = 2 * S;
  constexpr int DD = D * D;
  constexpr int l3 = 3;

  const float* dec  = (const float*)d_in[0];
  const float* enc  = (const float*)d_in[1];
  const float* sWq = (const float*)d_in[5]  + l3 * DD;
  const float* sWk = (const float*)d_in[6]  + l3 * DD;
  const float* sWv = (const float*)d_in[7]  + l3 * DD;
  const float* sWo = (const float*)d_in[8]  + l3 * DD;
  const float* cWq = (const float*)d_in[9]  + l3 * DD;
  const float* cWk = (const float*)d_in[10] + l3 * DD;
  const float* cWv = (const float*)d_in[11] + l3 * DD;
  const float* cWo = (const float*)d_in[12] + l3 * DD;
  const float* sbq = (const float*)d_in[13] + l3 * D;
  const float* sbk = (const float*)d_in[14] + l3 * D;
  const float* sbv = (const float*)d_in[15] + l3 * D;
  const float* sbo = (const float*)d_in[16] + l3 * D;
  const float* cbq = (const float*)d_in[17] + l3 * D;
  const float* cbk = (const float*)d_in[18] + l3 * D;
  const float* cbv = (const float*)d_in[19] + l3 * D;
  const float* cbo = (const float*)d_in[20] + l3 * D;
  const float* ln1g = (const float*)d_in[21] + l3 * D;
  const float* ln2g = (const float*)d_in[22] + l3 * D;
  const float* ln3g = (const float*)d_in[23] + l3 * D;
  const float* ln1b = (const float*)d_in[24] + l3 * D;
  const float* ln2b = (const float*)d_in[25] + l3 * D;
  const float* ln3b = (const float*)d_in[26] + l3 * D;
  const float* fW1 = (const float*)d_in[27] + (size_t)l3 * D * DF;
  const float* fb1 = (const float*)d_in[28] + l3 * DF;
  const float* fW2 = (const float*)d_in[29] + (size_t)l3 * DF * D;
  const float* fb2 = (const float*)d_in[30] + l3 * D;
  const float* Wout = (const float*)d_in[31];
  const float* bout = (const float*)d_in[32];
  float* out = (float*)d_out;

  uint8_t* wsp = (uint8_t*)d_ws;
  auto alloc = [&](size_t bytes) -> void* {
    void* p = wsp; wsp += (bytes + 255) & ~(size_t)255; return p;
  };
  float*          x0f  = (float*)alloc((size_t)M * D * 4);
  unsigned short* x0b  = (unsigned short*)alloc((size_t)M * D * 2);
  unsigned short* encb = (unsigned short*)alloc((size_t)M * D * 2);
  unsigned short* wqkv = (unsigned short*)alloc((size_t)3 * DD * 2);
  unsigned short* wos  = (unsigned short*)alloc((size_t)DD * 2);
  unsigned short* wqc  = (unsigned short*)alloc((size_t)DD * 2);
  unsigned short* wkvc = (unsigned short*)alloc((size_t)2 * DD * 2);
  unsigned short* woc  = (unsigned short*)alloc((size_t)DD * 2);
  unsigned short* wf1  = (unsigned short*)alloc((size_t)D * DF * 2);
  unsigned short* wf2  = (unsigned short*)alloc((size_t)D * DF * 2);
  unsigned short* wvo  = (unsigned short*)alloc((size_t)V * D * 2);
  float*          bqkv = (float*)alloc(3 * D * 4);
  float*          bkvc = (float*)alloc(2 * D * 4);
  unsigned short* qkv  = (unsigned short*)alloc((size_t)M * 3 * D * 2);
  unsigned short* attnb= (unsigned short*)alloc((size_t)M * D * 2);
  float*          oproj= (float*)alloc((size_t)M * D * 4);
  float*          a1f  = (float*)alloc((size_t)M * D * 4);
  unsigned short* a1b  = (unsigned short*)alloc((size_t)M * D * 2);
  unsigned short* qc   = (unsigned short*)alloc((size_t)M * D * 2);
  unsigned short* kvc  = (unsigned short*)alloc((size_t)M * 2 * D * 2);
  float*          a2f  = (float*)alloc((size_t)M * D * 4);
  unsigned short* a2b  = (unsigned short*)alloc((size_t)M * D * 2);
  unsigned short* ffh  = (unsigned short*)alloc((size_t)M * DF * 2);
  unsigned short* yb   = (unsigned short*)alloc((size_t)M * D * 2);

  build_x0<<<M * D / 4 / 256, 256, 0, stream>>>(dec, x0f, x0b);
  cvt_bf16_k<<<M * D / 4 / 256, 256, 0, stream>>>(enc, encb);

  TPtrs tp;
  tp.src[0] = sWq; tp.dst[0] = wqkv;
  tp.src[1] = sWk; tp.dst[1] = wqkv + DD;
  tp.src[2] = sWv; tp.dst[2] = wqkv + 2 * DD;
  tp.src[3] = sWo; tp.dst[3] = wos;
  tp.src[4] = cWq; tp.dst[4] = wqc;
  tp.src[5] = cWk; tp.dst[5] = wkvc;
  tp.src[6] = cWv; tp.dst[6] = wkvc + DD;
  tp.src[7] = cWo; tp.dst[7] = woc;
  transpose_cvt8<<<dim3(32, 16, 8), 256, 0, stream>>>(tp);
  transpose_cvt<<<dim3(DF/32, D/64), 256, 0, stream>>>(fW1, wf1, D, DF);
  transpose_cvt<<<dim3(D/32, DF/64), 256, 0, stream>>>(fW2, wf2, DF, D);
  transpose_cvt<<<dim3(V/32, D/64), 256, 0, stream>>>(Wout, wvo, D, V);
  copy_biases<<<20, 256, 0, stream>>>(sbq, sbk, sbv, cbk, cbv, bqkv, bkvc);

  // 3. self-attention block
  gemm32<128,1><<<(M/128)*(3*D/128), 256, 0, stream>>>(x0b, wqkv, bqkv, qkv, M, 3*D, D);
  attn_kernel<1><<<dim3(S/64, 32), 256, 0, stream>>>(qkv, 3*D, qkv + D, 3*D, qkv + 2*D, 3*D, attnb, D);
  gemm32<64,0><<<(M/128)*(D/64), 256, 0, stream>>>(attnb, wos, sbo, oproj, M, D, D);
  ln_kernel<<<M, 256, 0, stream>>>(x0f, oproj, ln1g, ln1b, a1f, a1b);

  // 4. cross-attention block
  gemm32<64,1><<<(M/128)*(D/64), 256, 0, stream>>>(a1b, wqc, cbq, qc, M, D, D);
  gemm32<128,1><<<(M/128)*(2*D/128), 256, 0, stream>>>(encb, wkvc, bkvc, kvc, M, 2*D, D);
  attn_kernel<0><<<dim3(S/64, 32), 256, 0, stream>>>(qc, D, kvc, 2*D, kvc + D, 2*D, attnb, D);
  gemm32<64,0><<<(M/128)*(D/64), 256, 0, stream>>>(attnb, woc, cbo, oproj, M, D, D);
  ln_kernel<<<M, 256, 0, stream>>>(a1f, oproj, ln2g, ln2b, a2f, a2b);

  // 5. FFN
  gemm32<256,2><<<(M/128)*(DF/256), 256, 0, stream>>>(a2b, wf1, fb1, ffh, M, DF, D);
  gemm32<64,0><<<(M/128)*(D/64), 256, 0, stream>>>(ffh, wf2, fb2, oproj, M, D, DF);
  ln_kernel<<<M, 256, 0, stream>>>(a2f, oproj, ln3g, ln3b, nullptr, yb);

  // 6. logits
  gemm32<256,3><<<(M/128)*(V/256), 256, 0, stream>>>(yb, wvo, bout, out, M, V, D);
}